// Round 21
// baseline (529.085 us; speedup 1.0000x reference)
//
#include <hip/hip_runtime.h>
#include <math.h>

#define DEV __device__ __forceinline__

typedef __attribute__((ext_vector_type(8))) short bf16x8;
typedef __attribute__((ext_vector_type(4))) float f32x4;

DEV float leakyf(float x, float s) { return x > 0.f ? x : s * x; }

DEV unsigned short f2bf(float f) {
  unsigned u = __float_as_uint(f);
  unsigned r = (u + 0x7fff + ((u >> 16) & 1)) >> 16;
  return (unsigned short)r;
}
DEV float bf2f(unsigned short h) { return __uint_as_float((unsigned)h << 16); }

DEV float sel4(float4 v, int h) {
  float a = (h & 1) ? v.y : v.x;
  float b = (h & 1) ? v.w : v.z;
  return (h & 2) ? b : a;
}

DEV float wave_sum(float v) {
#pragma unroll
  for (int o = 1; o < 64; o <<= 1) v += __shfl_xor(v, o);
  return v;
}
DEV float wave_max(float v) {
#pragma unroll
  for (int o = 1; o < 64; o <<= 1) v = fmaxf(v, __shfl_xor(v, o));
  return v;
}

// ---------------- weight pre-convert: W[K,Nc] f32 -> WT[Nc,K] bf16 ----------------
struct WJob { const float* in; unsigned short* out; int K; int Nc; };
struct WJobs { WJob j[13]; };

__global__ __launch_bounds__(256) void wt_kernel(WJobs jobs) {
  WJob jb = jobs.j[blockIdx.y];
  int total = jb.K * jb.Nc;
  for (int i = blockIdx.x * 256 + threadIdx.x; i < total; i += gridDim.x * 256) {
    int c = i / jb.K, k = i - c * jb.K;
    jb.out[i] = f2bf(jb.in[(size_t)k * jb.Nc + c]);
  }
}

// ---------------- BatchNorm (eval) ----------------
__global__ __launch_bounds__(256) void bn_kernel(
    const float* __restrict__ xin, const float* __restrict__ g,
    const float* __restrict__ b, const float* __restrict__ m,
    const float* __restrict__ v, float* __restrict__ xout, int total) {
  int i = blockIdx.x * 256 + threadIdx.x;
  if (i < total) {
    int c = i & 63;
    xout[i] = (xin[i] - m[c]) * rsqrtf(v[c] + 1e-5f) * g[c] + b[c];
  }
}

// ---------------- Edge encoder: fully-MFMA, persistent; writes rows into CSR order via inv[] ----------------
__global__ __launch_bounds__(256, 2) void edge_enc_kernel(
    const float* __restrict__ edge_attr, const unsigned short* __restrict__ WT1,
    const float* __restrict__ b1, const unsigned short* __restrict__ WT2,
    const float* __restrict__ b2, unsigned short* __restrict__ ea_csr,
    const int* __restrict__ inv, int E) {
  __shared__ unsigned short sEa1[64][136];  // bf16, pad 8
  int tid = threadIdx.x, lane = tid & 63, w = tid >> 6;
  int g = lane >> 4, q = lane & 15;
  bf16x8 w1f[8];
#pragma unroll
  for (int t = 0; t < 8; t++) {
    bf16x8 v = {};
    if (g < 2) v = *(const bf16x8*)(WT1 + (size_t)(16 * t + q) * 16 + 8 * g);
    w1f[t] = v;
  }
  float b1v[8];
#pragma unroll
  for (int t = 0; t < 8; t++) b1v[t] = b1[16 * t + q];
  bf16x8 w2f[4][4];
#pragma unroll
  for (int t = 0; t < 4; t++)
#pragma unroll
    for (int kc = 0; kc < 4; kc++)
      w2f[t][kc] = *(const bf16x8*)(WT2 + (size_t)(16 * t + q) * 128 + 32 * kc + 8 * g);
  float b2v[4];
#pragma unroll
  for (int t = 0; t < 4; t++) b2v[t] = b2[16 * t + q];

  int gstride = gridDim.x * 64;

  auto load_attr = [&](int base) -> bf16x8 {
    bf16x8 af = {};
    if (g < 2) {
      int e = base + w * 16 + q;
      if (e >= E) e = E - 1;
      const float* ap = edge_attr + (size_t)e * 16 + 8 * g;
      float4 x0 = *(const float4*)ap;
      float4 x1 = *(const float4*)(ap + 4);
      af[0] = (short)f2bf(x0.x); af[1] = (short)f2bf(x0.y);
      af[2] = (short)f2bf(x0.z); af[3] = (short)f2bf(x0.w);
      af[4] = (short)f2bf(x1.x); af[5] = (short)f2bf(x1.y);
      af[6] = (short)f2bf(x1.z); af[7] = (short)f2bf(x1.w);
    }
    return af;
  };

  int base = blockIdx.x * 64;
  if (base >= E) return;
  bf16x8 af = load_attr(base);
  for (; base < E; ) {
    int next = base + gstride;
    bf16x8 af_next = {};
    if (next < E) af_next = load_attr(next);  // prefetch overlaps with compute below
    int e0 = base + w * 16;
    f32x4 acc1[8];
#pragma unroll
    for (int t = 0; t < 8; t++) acc1[t] = (f32x4){0.f, 0.f, 0.f, 0.f};
#pragma unroll
    for (int t = 0; t < 8; t++)
      acc1[t] = __builtin_amdgcn_mfma_f32_16x16x32_bf16(af, w1f[t], acc1[t], 0, 0, 0);
#pragma unroll
    for (int t = 0; t < 8; t++)
#pragma unroll
      for (int r = 0; r < 4; r++) {
        float v = leakyf(acc1[t][r] + b1v[t], 0.01f);
        sEa1[w * 16 + g * 4 + r][16 * t + q] = f2bf(v);
      }
    f32x4 acc2[4];
#pragma unroll
    for (int t = 0; t < 4; t++) acc2[t] = (f32x4){0.f, 0.f, 0.f, 0.f};
#pragma unroll
    for (int kc = 0; kc < 4; kc++) {
      bf16x8 a2 = *(const bf16x8*)&sEa1[w * 16 + q][32 * kc + 8 * g];
#pragma unroll
      for (int t = 0; t < 4; t++)
        acc2[t] = __builtin_amdgcn_mfma_f32_16x16x32_bf16(a2, w2f[t][kc], acc2[t], 0, 0, 0);
    }
#pragma unroll
    for (int r = 0; r < 4; r++) {
      float vv[4];
      float p = 0.f;
#pragma unroll
      for (int t = 0; t < 4; t++) {
        float v = leakyf(acc2[t][r] + b2v[t], 0.01f);
        vv[t] = v;
        p += v * v;
      }
#pragma unroll
      for (int o = 1; o < 16; o <<= 1) p += __shfl_xor(p, o);
      float sc = 1.f / fmaxf(sqrtf(p), 1e-12f);
      int e = e0 + g * 4 + r;
      if (e < E) {
        int pos = inv[e];  // CSR position of this edge
#pragma unroll
        for (int t = 0; t < 4; t++)
          ea_csr[(size_t)pos * 64 + 16 * t + q] = f2bf(vv[t] * sc);
      }
    }
    af = af_next;
    base = next;
  }
}

// ---------------- CSR build ----------------
__global__ __launch_bounds__(256) void count_kernel(const int* __restrict__ dst0,
                                                    int* __restrict__ counts, int E, int E2) {
  int i = blockIdx.x * 256 + threadIdx.x;
  if (i < E2) {
    int d = (i < E) ? dst0[i] : (i - E);
    atomicAdd(&counts[d], 1);
  }
}

// 1024-thread block scan
__global__ __launch_bounds__(1024) void scan_kernel(const int* __restrict__ counts,
                                                    int* __restrict__ rowptr,
                                                    int* __restrict__ fill, int N) {
  __shared__ int part[1024];
  int tid = threadIdx.x;
  int chunk = (N + 1023) / 1024;
  int lo = tid * chunk, hi = lo + chunk;
  if (hi > N) hi = N;
  if (lo > N) lo = N;
  int s = 0;
  for (int i = lo; i < hi; i++) s += counts[i];
  part[tid] = s;
  __syncthreads();
#pragma unroll
  for (int o = 1; o < 1024; o <<= 1) {
    int v = (tid >= o) ? part[tid - o] : 0;
    __syncthreads();
    part[tid] += v;
    __syncthreads();
  }
  if (tid == 1023) rowptr[N] = part[1023];
  int off = part[tid] - s;  // exclusive prefix
  for (int i = lo; i < hi; i++) {
    rowptr[i] = off;
    fill[i] = off;
    off += counts[i];
  }
}

// builds csr (edge id), srcpos, dstpos by CSR position; inv (edge -> position)
__global__ __launch_bounds__(256) void fill_kernel(const int* __restrict__ src0,
                                                   const int* __restrict__ dst0,
                                                   int* __restrict__ fill,
                                                   int* __restrict__ csr,
                                                   int* __restrict__ srcpos,
                                                   int* __restrict__ dstpos,
                                                   int* __restrict__ inv, int E, int E2) {
  int i = blockIdx.x * 256 + threadIdx.x;
  if (i < E2) {
    int d, s;
    if (i < E) {
      d = dst0[i];
      s = src0[i];
    } else {
      d = s = i - E;
    }
    int pos = atomicAdd(&fill[d], 1);
    csr[pos] = i;
    srcpos[pos] = s;
    dstpos[pos] = d;
    inv[i] = pos;
  }
}

// ---------------- self-loop attr = mean of incoming encoded attrs (CSR-linear) ----------------
__global__ __launch_bounds__(256) void loopattr_kernel(unsigned short* __restrict__ ea_csr,
                                                       const int* __restrict__ rowptr,
                                                       const int* __restrict__ csr, int N, int E) {
  int lane = threadIdx.x & 63, wv = threadIdx.x >> 6;
  int stride = gridDim.x * 4;
  for (int n = blockIdx.x * 4 + wv; n < N; n += stride) {
    int r0 = rowptr[n], r1 = rowptr[n + 1];
    float acc = 0.f;
    int loop_pos = r0;
    for (int i = r0; i < r1; i++) {
      int e = csr[i];
      if (e < E) {
        acc += bf2f(ea_csr[(size_t)i * 64 + lane]);  // linear row read
      } else {
        loop_pos = i;
      }
    }
    int cnt = r1 - r0 - 1;  // real incoming edges (exactly one self-loop per node)
    ea_csr[(size_t)loop_pos * 64 + lane] = f2bf(acc / fmaxf((float)cnt, 1.f));
  }
}

// ---------------- bf16 MFMA GEMM (single) ----------------
// MODE: 0 f32 out, 1 bf16 out, 2 elu f32 out, 3 mix f32 out
template <int MODE>
__global__ __launch_bounds__(256) void gemm_mfma_kernel(
    const float* __restrict__ A, const unsigned short* __restrict__ BT,
    const float* __restrict__ bias, void* __restrict__ Cout, int M, int K, int Nc,
    const float* __restrict__ aux, const float* __restrict__ alpha_p) {
  __shared__ unsigned short sA[64][40];
  __shared__ unsigned short sB[64][40];
  int tid = threadIdx.x, lane = tid & 63, w = tid >> 6;
  int g = lane >> 4, q = lane & 15;
  int bm = blockIdx.y * 64, bn = blockIdx.x * 64;
  f32x4 acc[4];
#pragma unroll
  for (int t = 0; t < 4; t++) acc[t] = (f32x4){0.f, 0.f, 0.f, 0.f};
  int r = tid >> 2, ko = (tid & 3) * 8;
  for (int k0 = 0; k0 < K; k0 += 32) {
    {
      int gm = bm + r;
      bf16x8 v = {};
      if (gm < M) {
        const float* ap = A + (size_t)gm * K + k0 + ko;
        float4 x0 = *(const float4*)ap;
        float4 x1 = *(const float4*)(ap + 4);
        v[0] = (short)f2bf(x0.x); v[1] = (short)f2bf(x0.y);
        v[2] = (short)f2bf(x0.z); v[3] = (short)f2bf(x0.w);
        v[4] = (short)f2bf(x1.x); v[5] = (short)f2bf(x1.y);
        v[6] = (short)f2bf(x1.z); v[7] = (short)f2bf(x1.w);
      }
      *(bf16x8*)&sA[r][ko] = v;
      int gc = bn + r;
      bf16x8 bv = {};
      if (gc < Nc) bv = *(const bf16x8*)(BT + (size_t)gc * K + k0 + ko);
      *(bf16x8*)&sB[r][ko] = bv;
    }
    __syncthreads();
    bf16x8 a = *(const bf16x8*)&sA[w * 16 + q][8 * g];
#pragma unroll
    for (int t = 0; t < 4; t++) {
      bf16x8 b = *(const bf16x8*)&sB[16 * t + q][8 * g];
      acc[t] = __builtin_amdgcn_mfma_f32_16x16x32_bf16(a, b, acc[t], 0, 0, 0);
    }
    __syncthreads();
  }
  float s = 0.f;
  if (MODE == 3) s = 1.f / (1.f + __expf(-alpha_p[0]));
#pragma unroll
  for (int t = 0; t < 4; t++) {
    int col = bn + 16 * t + q;
#pragma unroll
    for (int rr = 0; rr < 4; rr++) {
      int row = bm + w * 16 + g * 4 + rr;
      if (row < M && col < Nc) {
        float v = acc[t][rr] + bias[col];
        if (MODE == 2) v = v > 0.f ? v : (__expf(v) - 1.f);
        if (MODE == 3) v = s * v + (1.f - s) * aux[(size_t)row * Nc + col];
        if (MODE == 1)
          ((unsigned short*)Cout)[(size_t)row * Nc + col] = f2bf(v);
        else
          ((float*)Cout)[(size_t)row * Nc + col] = v;
      }
    }
  }
}

// ---------------- bf16 MFMA GEMM (batched over grid.z) ----------------
struct GJob { const unsigned short* BT; const float* bias; void* out; int mode; };
struct GJobs { GJob j[3]; };

__global__ __launch_bounds__(256) void gemm_mfma_batched(
    const float* __restrict__ A, GJobs jobs, int M, int K, int Nc) {
  __shared__ unsigned short sA[64][40];
  __shared__ unsigned short sB[64][40];
  GJob jb = jobs.j[blockIdx.z];
  const unsigned short* BT = jb.BT;
  int tid = threadIdx.x, lane = tid & 63, w = tid >> 6;
  int g = lane >> 4, q = lane & 15;
  int bm = blockIdx.y * 64, bn = blockIdx.x * 64;
  f32x4 acc[4];
#pragma unroll
  for (int t = 0; t < 4; t++) acc[t] = (f32x4){0.f, 0.f, 0.f, 0.f};
  int r = tid >> 2, ko = (tid & 3) * 8;
  for (int k0 = 0; k0 < K; k0 += 32) {
    {
      int gm = bm + r;
      bf16x8 v = {};
      if (gm < M) {
        const float* ap = A + (size_t)gm * K + k0 + ko;
        float4 x0 = *(const float4*)ap;
        float4 x1 = *(const float4*)(ap + 4);
        v[0] = (short)f2bf(x0.x); v[1] = (short)f2bf(x0.y);
        v[2] = (short)f2bf(x0.z); v[3] = (short)f2bf(x0.w);
        v[4] = (short)f2bf(x1.x); v[5] = (short)f2bf(x1.y);
        v[6] = (short)f2bf(x1.z); v[7] = (short)f2bf(x1.w);
      }
      *(bf16x8*)&sA[r][ko] = v;
      int gc = bn + r;
      bf16x8 bv = {};
      if (gc < Nc) bv = *(const bf16x8*)(BT + (size_t)gc * K + k0 + ko);
      *(bf16x8*)&sB[r][ko] = bv;
    }
    __syncthreads();
    bf16x8 a = *(const bf16x8*)&sA[w * 16 + q][8 * g];
#pragma unroll
    for (int t = 0; t < 4; t++) {
      bf16x8 b = *(const bf16x8*)&sB[16 * t + q][8 * g];
      acc[t] = __builtin_amdgcn_mfma_f32_16x16x32_bf16(a, b, acc[t], 0, 0, 0);
    }
    __syncthreads();
  }
#pragma unroll
  for (int t = 0; t < 4; t++) {
    int col = bn + 16 * t + q;
#pragma unroll
    for (int rr = 0; rr < 4; rr++) {
      int row = bm + w * 16 + g * 4 + rr;
      if (row < M && col < Nc) {
        float v = acc[t][rr] + jb.bias[col];
        if (jb.mode == 1)
          ((unsigned short*)jb.out)[(size_t)row * Nc + col] = f2bf(v);
        else
          ((float*)jb.out)[(size_t)row * Nc + col] = v;
      }
    }
  }
}

// ---------------- GATv2 edge scores via MFMA; ea_csr read linearly (R18 epilogue) ----------------
template <int C, bool SPLIT>
__global__ __launch_bounds__(256) void score_mfma_kernel(
    const unsigned short* __restrict__ ea_csr, const unsigned short* __restrict__ xl,
    const unsigned short* __restrict__ xr, const float* __restrict__ We,
    const float* __restrict__ att, const int* __restrict__ srcpos,
    const int* __restrict__ dstpos,
    float* __restrict__ e_s, int E2, int HCfull, int col_off_in) {
  int lane = threadIdx.x & 63;
  int wv = threadIdx.x >> 6;
  int g = lane >> 4, q = lane & 15;
  int col_off = SPLIT ? (wv & 1) * 128 : col_off_in;
  bf16x8 bfrag[8][2];
#pragma unroll
  for (int t = 0; t < 8; t++)
#pragma unroll
    for (int kc = 0; kc < 2; kc++) {
      bf16x8 bv;
#pragma unroll
      for (int j = 0; j < 8; j++) {
        int k = kc * 32 + g * 8 + j;
        bv[j] = (short)f2bf(We[(size_t)k * HCfull + col_off + 16 * t + q]);
      }
      bfrag[t][kc] = bv;
    }
  float attv[8];
#pragma unroll
  for (int t = 0; t < 8; t++) attv[t] = att[col_off + 16 * t + q];

  constexpr int TPH = C / 16;
  constexpr int NH = 8 / TPH;
  const int headbase = col_off / C;

  int tiles = (E2 + 15) / 16;
  int tstart = SPLIT ? (blockIdx.x * 2 + (wv >> 1)) : (blockIdx.x * 4 + wv);
  int nw = SPLIT ? (gridDim.x * 2) : (gridDim.x * 4);
  for (int tile = tstart; tile < tiles; tile += nw) {
    int i0 = tile * 16;
    int ia = i0 + q;
    if (ia >= E2) ia = E2 - 1;
    const unsigned short* ap = ea_csr + (size_t)ia * 64 + g * 8;  // linear by CSR position
    bf16x8 a0 = *(const bf16x8*)(ap);
    bf16x8 a1 = *(const bf16x8*)(ap + 32);
    f32x4 acc[8];
#pragma unroll
    for (int t = 0; t < 8; t++) acc[t] = (f32x4){0.f, 0.f, 0.f, 0.f};
#pragma unroll
    for (int t = 0; t < 8; t++) {
      acc[t] = __builtin_amdgcn_mfma_f32_16x16x32_bf16(a0, bfrag[t][0], acc[t], 0, 0, 0);
      acc[t] = __builtin_amdgcn_mfma_f32_16x16x32_bf16(a1, bfrag[t][1], acc[t], 0, 0, 0);
    }
    int sn[4], dn[4];
#pragma unroll
    for (int r = 0; r < 4; r++) {
      int i = i0 + g * 4 + r;
      if (i >= E2) i = E2 - 1;
      sn[r] = srcpos[i];
      dn[r] = dstpos[i];
    }
    float p[NH][4];
#pragma unroll
    for (int hh = 0; hh < NH; hh++)
#pragma unroll
      for (int r = 0; r < 4; r++) p[hh][r] = 0.f;
#pragma unroll
    for (int t = 0; t < 8; t++) {
      int col = col_off + 16 * t + q;
#pragma unroll
      for (int r = 0; r < 4; r++) {
        float xv = bf2f(xl[(size_t)sn[r] * HCfull + col]) +
                   bf2f(xr[(size_t)dn[r] * HCfull + col]) + acc[t][r];
        xv = xv > 0.f ? xv : 0.2f * xv;
        p[t / TPH][r] += xv * attv[t];
      }
    }
#pragma unroll
    for (int hh = 0; hh < NH; hh++)
#pragma unroll
      for (int r = 0; r < 4; r++) {
#pragma unroll
        for (int o = 1; o < 16; o <<= 1) p[hh][r] += __shfl_xor(p[hh][r], o);
      }
    if (q == 0) {
#pragma unroll
      for (int r = 0; r < 4; r++) {
        int i = i0 + g * 4 + r;
        if (i < E2) {
#pragma unroll
          for (int hh = 0; hh < NH; hh++)
            e_s[(size_t)i * 4 + headbase + hh] = p[hh][r];
        }
      }
    }
  }
}

// ---------------- per-node softmax + aggregation; 4x-unrolled gather, register-only selects ----------------
template <int HC, bool L1MODE>
__global__ __launch_bounds__(256) void aggr_kernel(
    const float* __restrict__ e_s, const unsigned short* __restrict__ xl,
    const int* __restrict__ rowptr, const int* __restrict__ srcpos,
    const float* __restrict__ bias,
    const float* __restrict__ lng, const float* __restrict__ lnb,
    float* __restrict__ xout,
    float* __restrict__ x1out, const float* __restrict__ skipproj,
    float* __restrict__ md, int N) {
  constexpr int CPL = HC / 64;
  int lane = threadIdx.x & 63, wv = threadIdx.x >> 6;
  int stride = gridDim.x * 4;
  const float4* e_s4 = (const float4*)e_s;
  for (int n = blockIdx.x * 4 + wv; n < N; n += stride) {
    int r0 = rowptr[n], r1 = rowptr[n + 1];
    float m0 = -1e30f, m1 = -1e30f, m2 = -1e30f, m3 = -1e30f;
    for (int i = r0 + lane; i < r1; i += 64) {
      float4 v = e_s4[i];
      m0 = fmaxf(m0, v.x);
      m1 = fmaxf(m1, v.y);
      m2 = fmaxf(m2, v.z);
      m3 = fmaxf(m3, v.w);
    }
    m0 = wave_max(m0);
    m1 = wave_max(m1);
    m2 = wave_max(m2);
    m3 = wave_max(m3);
    float d0 = 0.f, d1 = 0.f, d2 = 0.f, d3 = 0.f;
    for (int i = r0 + lane; i < r1; i += 64) {
      float4 v = e_s4[i];
      d0 += __expf(v.x - m0);
      d1 += __expf(v.y - m1);
      d2 += __expf(v.z - m2);
      d3 += __expf(v.w - m3);
    }
    d0 = wave_sum(d0);
    d1 = wave_sum(d1);
    d2 = wave_sum(d2);
    d3 = wave_sum(d3);
    float i0 = 1.f / (d0 + 1e-16f), i1 = 1.f / (d1 + 1e-16f);
    float i2 = 1.f / (d2 + 1e-16f), i3 = 1.f / (d3 + 1e-16f);
    if (lane == 0) {
      float* mp = md + (size_t)n * 8;
      mp[0] = m0; mp[1] = m1; mp[2] = m2; mp[3] = m3;
      mp[4] = i0; mp[5] = i1; mp[6] = i2; mp[7] = i3;
    }
    int h = lane >> 4;
    float mh = (h & 2) ? ((h & 1) ? m3 : m2) : ((h & 1) ? m1 : m0);
    float ih = (h & 2) ? ((h & 1) ? i3 : i2) : ((h & 1) ? i1 : i0);
    float acc[CPL];
#pragma unroll
    for (int j = 0; j < CPL; j++) acc[j] = 0.f;
    int c0 = lane * CPL;
    int i = r0;
    for (; i + 4 <= r1; i += 4) {
      float sh0, sh1, sh2, sh3;
      int sn0, sn1, sn2, sn3;
      {
        float4 a = e_s4[i], b = e_s4[i + 1], c = e_s4[i + 2], d = e_s4[i + 3];
        sh0 = sel4(a, h); sh1 = sel4(b, h); sh2 = sel4(c, h); sh3 = sel4(d, h);
      }
      sn0 = srcpos[i]; sn1 = srcpos[i + 1]; sn2 = srcpos[i + 2]; sn3 = srcpos[i + 3];
      if constexpr (CPL == 2) {
        ushort2 t0 = *(const ushort2*)(xl + (size_t)sn0 * HC + c0);
        ushort2 t1 = *(const ushort2*)(xl + (size_t)sn1 * HC + c0);
        ushort2 t2 = *(const ushort2*)(xl + (size_t)sn2 * HC + c0);
        ushort2 t3 = *(const ushort2*)(xl + (size_t)sn3 * HC + c0);
        float a0 = __expf(sh0 - mh) * ih;
        float a1 = __expf(sh1 - mh) * ih;
        float a2 = __expf(sh2 - mh) * ih;
        float a3 = __expf(sh3 - mh) * ih;
        acc[0] += a0 * bf2f(t0.x) + a1 * bf2f(t1.x) + a2 * bf2f(t2.x) + a3 * bf2f(t3.x);
        acc[1] += a0 * bf2f(t0.y) + a1 * bf2f(t1.y) + a2 * bf2f(t2.y) + a3 * bf2f(t3.y);
      } else {
        ushort4 t0 = *(const ushort4*)(xl + (size_t)sn0 * HC + c0);
        ushort4 t1 = *(const ushort4*)(xl + (size_t)sn1 * HC + c0);
        ushort4 t2 = *(const ushort4*)(xl + (size_t)sn2 * HC + c0);
        ushort4 t3 = *(const ushort4*)(xl + (size_t)sn3 * HC + c0);
        float a0 = __expf(sh0 - mh) * ih;
        float a1 = __expf(sh1 - mh) * ih;
        float a2 = __expf(sh2 - mh) * ih;
        float a3 = __expf(sh3 - mh) * ih;
        acc[0] += a0 * bf2f(t0.x) + a1 * bf2f(t1.x) + a2 * bf2f(t2.x) + a3 * bf2f(t3.x);
        acc[1] += a0 * bf2f(t0.y) + a1 * bf2f(t1.y) + a2 * bf2f(t2.y) + a3 * bf2f(t3.y);
        acc[2] += a0 * bf2f(t0.z) + a1 * bf2f(t1.z) + a2 * bf2f(t2.z) + a3 * bf2f(t3.z);
        acc[3] += a0 * bf2f(t0.w) + a1 * bf2f(t1.w) + a2 * bf2f(t2.w) + a3 * bf2f(t3.w);
      }
    }
    for (; i < r1; i++) {
      float sh = sel4(e_s4[i], h);
      float a = __expf(sh - mh) * ih;
      int sn = srcpos[i];
      const unsigned short* xp = xl + (size_t)sn * HC + c0;
      if constexpr (CPL == 2) {
        ushort2 t = *(const ushort2*)xp;
        acc[0] += a * bf2f(t.x);
        acc[1] += a * bf2f(t.y);
      } else {
        ushort4 t = *(const ushort4*)xp;
        acc[0] += a * bf2f(t.x);
        acc[1] += a * bf2f(t.y);
        acc[2] += a * bf2f(t.z);
        acc[3] += a * bf2f(t.w);
      }
    }
    float vals[CPL];
    float vs = 0.f, vq = 0.f;
#pragma unroll
    for (int j = 0; j < CPL; j++) {
      float t = acc[j] + bias[c0 + j];
      vals[j] = t;
      vs += t;
      vq += t * t;
    }
    vs = wave_sum(vs);
    vq = wave_sum(vq);
    float mean = vs * (1.f / HC);
    float var = vq * (1.f / HC) - mean * mean;
    float rstd = rsqrtf(fmaxf(var, 0.f) + 1e-5f);
#pragma unroll
    for (int j = 0; j < CPL; j++) {
      int c = c0 + j;
      float y = (vals[j] - mean) * rstd * lng[c] + lnb[c];
      y = leakyf(y, 0.01f);
      if constexpr (L1MODE) {
        x1out[(size_t)n * HC + c] = y;
        xout[(size_t)n * HC + c] = 0.01f * skipproj[(size_t)n * HC + c] + y;
      } else {
        xout[(size_t)n * HC + c] = y;
      }
    }
  }
}

// ---------------- alpha: coalesced e_s/dstpos read, md L2-hit, one scattered 16B write ----------------
__global__ __launch_bounds__(256) void alpha_kernel(
    const float* __restrict__ e_s, const int* __restrict__ csr,
    const int* __restrict__ dstpos, const float* __restrict__ md,
    float* __restrict__ alpha_out, int E2) {
  int i = blockIdx.x * 256 + threadIdx.x;
  if (i < E2) {
    float4 sv = ((const float4*)e_s)[i];
    int d = dstpos[i];
    const float* mp = md + (size_t)d * 8;
    float4 a;
    a.x = __expf(sv.x - mp[0]) * mp[4];
    a.y = __expf(sv.y - mp[1]) * mp[5];
    a.z = __expf(sv.z - mp[2]) * mp[6];
    a.w = __expf(sv.w - mp[3]) * mp[7];
    ((float4*)alpha_out)[csr[i]] = a;
  }
}

extern "C" void kernel_launch(void* const* d_in, const int* in_sizes, int n_in,
                              void* d_out, int out_size, void* d_ws, size_t ws_size,
                              hipStream_t stream) {
  (void)n_in;
  (void)out_size;
  (void)ws_size;
  const float* x_in = (const float*)d_in[0];
  const int* edge_index = (const int*)d_in[1];
  const float* edge_attr = (const float*)d_in[2];
  const float* bn0_g = (const float*)d_in[3];
  const float* bn0_b = (const float*)d_in[4];
  const float* bn0_m = (const float*)d_in[5];
  const float* bn0_v = (const float*)d_in[6];
  const float* eeW1 = (const float*)d_in[7];
  const float* eeb1 = (const float*)d_in[8];
  const float* eeW2 = (const float*)d_in[9];
  const float* eeb2 = (const float*)d_in[10];
  const float* g1_Wl = (const float*)d_in[11];
  const float* g1_bl = (const float*)d_in[12];
  const float* g1_Wr = (const float*)d_in[13];
  const float* g1_br = (const float*)d_in[14];
  const float* g1_We = (const float*)d_in[15];
  const float* g1_att = (const float*)d_in[16];
  const float* g1_bias = (const float*)d_in[17];
  const float* g2_Wl = (const float*)d_in[18];
  const float* g2_bl = (const float*)d_in[19];
  const float* g2_Wr = (const float*)d_in[20];
  const float* g2_br = (const float*)d_in[21];
  const float* g2_We = (const float*)d_in[22];
  const float* g2_att = (const float*)d_in[23];
  const float* g2_bias = (const float*)d_in[24];
  const float* g3_Wl = (const float*)d_in[25];
  const float* g3_bl = (const float*)d_in[26];
  const float* g3_Wr = (const float*)d_in[27];
  const float* g3_br = (const float*)d_in[28];
  const float* g3_We = (const float*)d_in[29];
  const float* g3_att = (const float*)d_in[30];
  const float* g3_bias = (const float*)d_in[31];
  const float* ln1_g = (const float*)d_in[32];
  const float* ln1_b = (const float*)d_in[33];
  const float* ln2_g = (const float*)d_in[34];
  const float* ln2_b = (const float*)d_in[35];
  const float* ln3_g = (const float*)d_in[36];
  const float* ln3_b = (const float*)d_in[37];
  const float* skip_W = (const float*)d_in[38];
  const float* skip_b = (const float*)d_in[39];
  const float* alpha_p = (const float*)d_in[40];
  const float* fp_W = (const float*)d_in[41];
  const float* fp_b = (const float*)d_in[42];
  const float* np_W1 = (const float*)d_in[43];
  const float* np_b1 = (const float*)d_in[44];
  const float* np_W2 = (const float*)d_in[45];
  const float* np_b2 = (const float*)d_in[46];
  const float* np_W3 = (const float*)d_in[47];
  const float* np_b3 = (const float*)d_in[48];

  const int N = in_sizes[0] / 64;
  const int E = in_sizes[2] / 16;
  const int E2 = E + N;
  const int* src0 = edge_index;
  const int* dst0 = edge_index + E;

  float* ws = (float*)d_ws;
  size_t off = 0;
  float* x = ws + off;         off += (size_t)N * 64;
  unsigned short* ea_csr = (unsigned short*)(ws + off); off += (size_t)E2 * 32;
  unsigned short* xl = (unsigned short*)(ws + off);    off += (size_t)N * 128;
  unsigned short* xr = (unsigned short*)(ws + off);    off += (size_t)N * 128;
  float* skipproj = ws + off;  off += (size_t)N * 128;  // reused as h1 at the end
  float* x1 = ws + off;        off += (size_t)N * 128;
  float* skip1 = ws + off;     off += (size_t)N * 128;
  float* x2 = ws + off;        off += (size_t)N * 128;
  float* x3 = ws + off;        off += (size_t)N * 256;
  float* e_s = ws + off;       off += (size_t)E2 * 4;
  float* h2 = ws + off;        off += (size_t)N * 64;
  float* md = ws + off;        off += (size_t)N * 8;
  int* counts = (int*)(ws + off);
  int* rowptr = counts + N;
  int* fill = rowptr + N + 1;
  int* csr = fill + N;
  int* srcpos = csr + E2;
  int* dstpos = srcpos + E2;
  int* inv = dstpos + E2;
  off += (size_t)(3 * N + 1 + 4 * E2);
  off = (off + 3) & ~(size_t)3;
  unsigned short* wtp = (unsigned short*)(ws + off);
  auto alloc_wt = [&](int elems) {
    unsigned short* p = wtp;
    wtp += (elems + 7) & ~7;
    return p;
  };
  unsigned short* wt_g1l = alloc_wt(64 * 128);
  unsigned short* wt_g1r = alloc_wt(64 * 128);
  unsigned short* wt_skip = alloc_wt(64 * 128);
  unsigned short* wt_g2l = alloc_wt(128 * 128);
  unsigned short* wt_g2r = alloc_wt(128 * 128);
  unsigned short* wt_g3l = alloc_wt(128 * 256);
  unsigned short* wt_g3r = alloc_wt(128 * 256);
  unsigned short* wt_fp = alloc_wt(128 * 256);
  unsigned short* wt_np1 = alloc_wt(256 * 128);
  unsigned short* wt_np2 = alloc_wt(128 * 64);
  unsigned short* wt_np3 = alloc_wt(64 * 1);
  unsigned short* wt_ee1 = alloc_wt(16 * 128);
  unsigned short* wt_ee2 = alloc_wt(128 * 64);

  float* out = (float*)d_out;
  float* xf = out;
  float* npout = out + (size_t)N * 256;
  float* a1 = npout + N;
  float* a2 = a1 + (size_t)E2 * 4;
  float* a3 = a2 + (size_t)E2 * 4;

  WJobs jobs;
  jobs.j[0] = {g1_Wl, wt_g1l, 64, 128};
  jobs.j[1] = {g1_Wr, wt_g1r, 64, 128};
  jobs.j[2] = {skip_W, wt_skip, 64, 128};
  jobs.j[3] = {g2_Wl, wt_g2l, 128, 128};
  jobs.j[4] = {g2_Wr, wt_g2r, 128, 128};
  jobs.j[5] = {g3_Wl, wt_g3l, 128, 256};
  jobs.j[6] = {g3_Wr, wt_g3r, 128, 256};
  jobs.j[7] = {fp_W, wt_fp, 128, 256};
  jobs.j[8] = {np_W1, wt_np1, 256, 128};
  jobs.j[9] = {np_W2, wt_np2, 128, 64};
  jobs.j[10] = {np_W3, wt_np3, 64, 1};
  jobs.j[11] = {eeW1, wt_ee1, 16, 128};
  jobs.j[12] = {eeW2, wt_ee2, 128, 64};

  hipMemsetAsync(counts, 0, (size_t)N * sizeof(int), stream);
  wt_kernel<<<dim3(64, 13), 256, 0, stream>>>(jobs);
  bn_kernel<<<(N * 64 + 255) / 256, 256, 0, stream>>>(x_in, bn0_g, bn0_b, bn0_m, bn0_v, x, N * 64);
  count_kernel<<<(E2 + 255) / 256, 256, 0, stream>>>(dst0, counts, E, E2);
  scan_kernel<<<1, 1024, 0, stream>>>(counts, rowptr, fill, N);
  fill_kernel<<<(E2 + 255) / 256, 256, 0, stream>>>(src0, dst0, fill, csr, srcpos, dstpos, inv, E, E2);
  edge_enc_kernel<<<1280, 256, 0, stream>>>(edge_attr, wt_ee1, eeb1, wt_ee2, eeb2, ea_csr, inv, E);
  loopattr_kernel<<<(N + 3) / 4, 256, 0, stream>>>(ea_csr, rowptr, csr, N, E);

  auto gemm = [&](int mode, const float* A, const unsigned short* BT, const float* bias,
                  void* Cp, int M, int K, int Nc, const float* aux) {
    dim3 gdim((Nc + 63) / 64, (M + 63) / 64);
    switch (mode) {
      case 0: gemm_mfma_kernel<0><<<gdim, 256, 0, stream>>>(A, BT, bias, Cp, M, K, Nc, nullptr, nullptr); break;
      case 2: gemm_mfma_kernel<2><<<gdim, 256, 0, stream>>>(A, BT, bias, Cp, M, K, Nc, nullptr, nullptr); break;
      case 3: gemm_mfma_kernel<3><<<gdim, 256, 0, stream>>>(A, BT, bias, Cp, M, K, Nc, aux, alpha_p); break;
    }
  };
  auto gemm_batch = [&](const float* A, int M, int K, int Nc, GJobs gj, int nz) {
    dim3 gdim((Nc + 63) / 64, (M + 63) / 64, nz);
    gemm_mfma_batched<<<gdim, 256, 0, stream>>>(A, gj, M, K, Nc);
  };

  const int nblk_node = (N + 3) / 4;
  const int score_blocks = 2560;
  const int nblk_edge = (E2 + 255) / 256;

  // ---- Layer 1 (din=64, HC=128, C=32) ----
  {
    GJobs gj;
    gj.j[0] = {wt_g1l, g1_bl, xl, 1};
    gj.j[1] = {wt_g1r, g1_br, xr, 1};
    gj.j[2] = {wt_skip, skip_b, skipproj, 0};
    gemm_batch(x, N, 64, 128, gj, 3);
  }
  score_mfma_kernel<32, false><<<score_blocks, 256, 0, stream>>>(ea_csr, xl, xr, g1_We, g1_att, srcpos, dstpos, e_s, E2, 128, 0);
  aggr_kernel<128, true><<<nblk_node, 256, 0, stream>>>(e_s, xl, rowptr, srcpos, g1_bias, ln1_g, ln1_b,
                                                        skip1, x1, skipproj, md, N);
  alpha_kernel<<<nblk_edge, 256, 0, stream>>>(e_s, csr, dstpos, md, a1, E2);
  // ---- Layer 2 (din=128, HC=128, C=32) ----
  {
    GJobs gj;
    gj.j[0] = {wt_g2l, g2_bl, xl, 1};
    gj.j[1] = {wt_g2r, g2_br, xr, 1};
    gj.j[2] = {nullptr, nullptr, nullptr, 0};
    gemm_batch(skip1, N, 128, 128, gj, 2);
  }
  score_mfma_kernel<32, false><<<score_blocks, 256, 0, stream>>>(ea_csr, xl, xr, g2_We, g2_att, srcpos, dstpos, e_s, E2, 128, 0);
  aggr_kernel<128, false><<<nblk_node, 256, 0, stream>>>(e_s, xl, rowptr, srcpos, g2_bias, ln2_g, ln2_b,
                                                         x2, nullptr, nullptr, md, N);
  alpha_kernel<<<nblk_edge, 256, 0, stream>>>(e_s, csr, dstpos, md, a2, E2);
  // ---- Layer 3 (din=128, HC=256, C=64): one launch, wave-split col halves ----
  {
    GJobs gj;
    gj.j[0] = {wt_g3l, g3_bl, xl, 1};
    gj.j[1] = {wt_g3r, g3_br, xr, 1};
    gj.j[2] = {nullptr, nullptr, nullptr, 0};
    gemm_batch(x2, N, 128, 256, gj, 2);
  }
  score_mfma_kernel<64, true><<<score_blocks, 256, 0, stream>>>(ea_csr, xl, xr, g3_We, g3_att, srcpos, dstpos, e_s, E2, 256, 0);
  aggr_kernel<256, false><<<nblk_node, 256, 0, stream>>>(e_s, xl, rowptr, srcpos, g3_bias, ln3_g, ln3_b,
                                                         x3, nullptr, nullptr, md, N);
  alpha_kernel<<<nblk_edge, 256, 0, stream>>>(e_s, csr, dstpos, md, a3, E2);
  // ---- Final: xf = s*(x1@fp_W+fp_b) + (1-s)*x3 ; node MLP ----
  gemm(3, x1, wt_fp, fp_b, xf, N, 128, 256, x3);
  gemm(2, xf, wt_np1, np_b1, skipproj, N, 256, 128, nullptr);   // h1
  gemm(2, skipproj, wt_np2, np_b2, h2, N, 128, 64, nullptr);    // h2
  gemm(0, h2, wt_np3, np_b3, npout, N, 64, 1, nullptr);
}

// Round 22
// 510.702 us; speedup vs baseline: 1.0360x; 1.0360x over previous
//
#include <hip/hip_runtime.h>
#include <math.h>

#define DEV __device__ __forceinline__

typedef __attribute__((ext_vector_type(8))) short bf16x8;
typedef __attribute__((ext_vector_type(4))) float f32x4;

DEV float leakyf(float x, float s) { return x > 0.f ? x : s * x; }

DEV unsigned short f2bf(float f) {
  unsigned u = __float_as_uint(f);
  unsigned r = (u + 0x7fff + ((u >> 16) & 1)) >> 16;
  return (unsigned short)r;
}
DEV float bf2f(unsigned short h) { return __uint_as_float((unsigned)h << 16); }

DEV float sel4(float4 v, int h) {
  float a = (h & 1) ? v.y : v.x;
  float b = (h & 1) ? v.w : v.z;
  return (h & 2) ? b : a;
}

DEV float wave_sum(float v) {
#pragma unroll
  for (int o = 1; o < 64; o <<= 1) v += __shfl_xor(v, o);
  return v;
}

// ---------------- weight pre-convert: W[K,Nc] f32 -> WT[Nc,K] bf16 ----------------
struct WJob { const float* in; unsigned short* out; int K; int Nc; };
struct WJobs { WJob j[13]; };

__global__ __launch_bounds__(256) void wt_kernel(WJobs jobs) {
  WJob jb = jobs.j[blockIdx.y];
  int total = jb.K * jb.Nc;
  for (int i = blockIdx.x * 256 + threadIdx.x; i < total; i += gridDim.x * 256) {
    int c = i / jb.K, k = i - c * jb.K;
    jb.out[i] = f2bf(jb.in[(size_t)k * jb.Nc + c]);
  }
}

// ---------------- BatchNorm (eval) ----------------
__global__ __launch_bounds__(256) void bn_kernel(
    const float* __restrict__ xin, const float* __restrict__ g,
    const float* __restrict__ b, const float* __restrict__ m,
    const float* __restrict__ v, float* __restrict__ xout, int total) {
  int i = blockIdx.x * 256 + threadIdx.x;
  if (i < total) {
    int c = i & 63;
    xout[i] = (xin[i] - m[c]) * rsqrtf(v[c] + 1e-5f) * g[c] + b[c];
  }
}

// ---------------- Edge encoder: fully-MFMA, persistent; writes rows into CSR order via inv[] ----------------
__global__ __launch_bounds__(256, 2) void edge_enc_kernel(
    const float* __restrict__ edge_attr, const unsigned short* __restrict__ WT1,
    const float* __restrict__ b1, const unsigned short* __restrict__ WT2,
    const float* __restrict__ b2, unsigned short* __restrict__ ea_csr,
    const int* __restrict__ inv, int E) {
  __shared__ unsigned short sEa1[64][136];  // bf16, pad 8
  int tid = threadIdx.x, lane = tid & 63, w = tid >> 6;
  int g = lane >> 4, q = lane & 15;
  bf16x8 w1f[8];
#pragma unroll
  for (int t = 0; t < 8; t++) {
    bf16x8 v = {};
    if (g < 2) v = *(const bf16x8*)(WT1 + (size_t)(16 * t + q) * 16 + 8 * g);
    w1f[t] = v;
  }
  float b1v[8];
#pragma unroll
  for (int t = 0; t < 8; t++) b1v[t] = b1[16 * t + q];
  bf16x8 w2f[4][4];
#pragma unroll
  for (int t = 0; t < 4; t++)
#pragma unroll
    for (int kc = 0; kc < 4; kc++)
      w2f[t][kc] = *(const bf16x8*)(WT2 + (size_t)(16 * t + q) * 128 + 32 * kc + 8 * g);
  float b2v[4];
#pragma unroll
  for (int t = 0; t < 4; t++) b2v[t] = b2[16 * t + q];

  int gstride = gridDim.x * 64;

  auto load_attr = [&](int base) -> bf16x8 {
    bf16x8 af = {};
    if (g < 2) {
      int e = base + w * 16 + q;
      if (e >= E) e = E - 1;
      const float* ap = edge_attr + (size_t)e * 16 + 8 * g;
      float4 x0 = *(const float4*)ap;
      float4 x1 = *(const float4*)(ap + 4);
      af[0] = (short)f2bf(x0.x); af[1] = (short)f2bf(x0.y);
      af[2] = (short)f2bf(x0.z); af[3] = (short)f2bf(x0.w);
      af[4] = (short)f2bf(x1.x); af[5] = (short)f2bf(x1.y);
      af[6] = (short)f2bf(x1.z); af[7] = (short)f2bf(x1.w);
    }
    return af;
  };

  int base = blockIdx.x * 64;
  if (base >= E) return;
  bf16x8 af = load_attr(base);
  for (; base < E; ) {
    int next = base + gstride;
    bf16x8 af_next = {};
    if (next < E) af_next = load_attr(next);  // prefetch overlaps with compute below
    int e0 = base + w * 16;
    f32x4 acc1[8];
#pragma unroll
    for (int t = 0; t < 8; t++) acc1[t] = (f32x4){0.f, 0.f, 0.f, 0.f};
#pragma unroll
    for (int t = 0; t < 8; t++)
      acc1[t] = __builtin_amdgcn_mfma_f32_16x16x32_bf16(af, w1f[t], acc1[t], 0, 0, 0);
#pragma unroll
    for (int t = 0; t < 8; t++)
#pragma unroll
      for (int r = 0; r < 4; r++) {
        float v = leakyf(acc1[t][r] + b1v[t], 0.01f);
        sEa1[w * 16 + g * 4 + r][16 * t + q] = f2bf(v);
      }
    f32x4 acc2[4];
#pragma unroll
    for (int t = 0; t < 4; t++) acc2[t] = (f32x4){0.f, 0.f, 0.f, 0.f};
#pragma unroll
    for (int kc = 0; kc < 4; kc++) {
      bf16x8 a2 = *(const bf16x8*)&sEa1[w * 16 + q][32 * kc + 8 * g];
#pragma unroll
      for (int t = 0; t < 4; t++)
        acc2[t] = __builtin_amdgcn_mfma_f32_16x16x32_bf16(a2, w2f[t][kc], acc2[t], 0, 0, 0);
    }
#pragma unroll
    for (int r = 0; r < 4; r++) {
      float vv[4];
      float p = 0.f;
#pragma unroll
      for (int t = 0; t < 4; t++) {
        float v = leakyf(acc2[t][r] + b2v[t], 0.01f);
        vv[t] = v;
        p += v * v;
      }
#pragma unroll
      for (int o = 1; o < 16; o <<= 1) p += __shfl_xor(p, o);
      float sc = 1.f / fmaxf(sqrtf(p), 1e-12f);
      int e = e0 + g * 4 + r;
      if (e < E) {
        int pos = inv[e];  // CSR position of this edge
#pragma unroll
        for (int t = 0; t < 4; t++)
          ea_csr[(size_t)pos * 64 + 16 * t + q] = f2bf(vv[t] * sc);
      }
    }
    af = af_next;
    base = next;
  }
}

// ---------------- CSR build ----------------
__global__ __launch_bounds__(256) void count_kernel(const int* __restrict__ dst0,
                                                    int* __restrict__ counts, int E, int E2) {
  int i = blockIdx.x * 256 + threadIdx.x;
  if (i < E2) {
    int d = (i < E) ? dst0[i] : (i - E);
    atomicAdd(&counts[d], 1);
  }
}

// 1024-thread block scan
__global__ __launch_bounds__(1024) void scan_kernel(const int* __restrict__ counts,
                                                    int* __restrict__ rowptr,
                                                    int* __restrict__ fill, int N) {
  __shared__ int part[1024];
  int tid = threadIdx.x;
  int chunk = (N + 1023) / 1024;
  int lo = tid * chunk, hi = lo + chunk;
  if (hi > N) hi = N;
  if (lo > N) lo = N;
  int s = 0;
  for (int i = lo; i < hi; i++) s += counts[i];
  part[tid] = s;
  __syncthreads();
#pragma unroll
  for (int o = 1; o < 1024; o <<= 1) {
    int v = (tid >= o) ? part[tid - o] : 0;
    __syncthreads();
    part[tid] += v;
    __syncthreads();
  }
  if (tid == 1023) rowptr[N] = part[1023];
  int off = part[tid] - s;  // exclusive prefix
  for (int i = lo; i < hi; i++) {
    rowptr[i] = off;
    fill[i] = off;
    off += counts[i];
  }
}

// builds csr (edge id), srcpos, dstpos by CSR position; inv (edge -> position)
__global__ __launch_bounds__(256) void fill_kernel(const int* __restrict__ src0,
                                                   const int* __restrict__ dst0,
                                                   int* __restrict__ fill,
                                                   int* __restrict__ csr,
                                                   int* __restrict__ srcpos,
                                                   int* __restrict__ dstpos,
                                                   int* __restrict__ inv, int E, int E2) {
  int i = blockIdx.x * 256 + threadIdx.x;
  if (i < E2) {
    int d, s;
    if (i < E) {
      d = dst0[i];
      s = src0[i];
    } else {
      d = s = i - E;
    }
    int pos = atomicAdd(&fill[d], 1);
    csr[pos] = i;
    srcpos[pos] = s;
    dstpos[pos] = d;
    inv[i] = pos;
  }
}

// ---------------- self-loop attr = mean of incoming encoded attrs (CSR-linear) ----------------
__global__ __launch_bounds__(256) void loopattr_kernel(unsigned short* __restrict__ ea_csr,
                                                       const int* __restrict__ rowptr,
                                                       const int* __restrict__ csr, int N, int E) {
  int lane = threadIdx.x & 63, wv = threadIdx.x >> 6;
  int stride = gridDim.x * 4;
  for (int n = blockIdx.x * 4 + wv; n < N; n += stride) {
    int r0 = rowptr[n], r1 = rowptr[n + 1];
    float acc = 0.f;
    int loop_pos = r0;
    for (int i = r0; i < r1; i++) {
      int e = csr[i];
      if (e < E) {
        acc += bf2f(ea_csr[(size_t)i * 64 + lane]);  // linear row read
      } else {
        loop_pos = i;
      }
    }
    int cnt = r1 - r0 - 1;  // real incoming edges (exactly one self-loop per node)
    ea_csr[(size_t)loop_pos * 64 + lane] = f2bf(acc / fmaxf((float)cnt, 1.f));
  }
}

// ---------------- bf16 MFMA GEMM (single) ----------------
// MODE: 0 f32 out, 1 bf16 out, 2 elu f32 out, 3 mix f32 out
template <int MODE>
__global__ __launch_bounds__(256) void gemm_mfma_kernel(
    const float* __restrict__ A, const unsigned short* __restrict__ BT,
    const float* __restrict__ bias, void* __restrict__ Cout, int M, int K, int Nc,
    const float* __restrict__ aux, const float* __restrict__ alpha_p) {
  __shared__ unsigned short sA[64][40];
  __shared__ unsigned short sB[64][40];
  int tid = threadIdx.x, lane = tid & 63, w = tid >> 6;
  int g = lane >> 4, q = lane & 15;
  int bm = blockIdx.y * 64, bn = blockIdx.x * 64;
  f32x4 acc[4];
#pragma unroll
  for (int t = 0; t < 4; t++) acc[t] = (f32x4){0.f, 0.f, 0.f, 0.f};
  int r = tid >> 2, ko = (tid & 3) * 8;
  for (int k0 = 0; k0 < K; k0 += 32) {
    {
      int gm = bm + r;
      bf16x8 v = {};
      if (gm < M) {
        const float* ap = A + (size_t)gm * K + k0 + ko;
        float4 x0 = *(const float4*)ap;
        float4 x1 = *(const float4*)(ap + 4);
        v[0] = (short)f2bf(x0.x); v[1] = (short)f2bf(x0.y);
        v[2] = (short)f2bf(x0.z); v[3] = (short)f2bf(x0.w);
        v[4] = (short)f2bf(x1.x); v[5] = (short)f2bf(x1.y);
        v[6] = (short)f2bf(x1.z); v[7] = (short)f2bf(x1.w);
      }
      *(bf16x8*)&sA[r][ko] = v;
      int gc = bn + r;
      bf16x8 bv = {};
      if (gc < Nc) bv = *(const bf16x8*)(BT + (size_t)gc * K + k0 + ko);
      *(bf16x8*)&sB[r][ko] = bv;
    }
    __syncthreads();
    bf16x8 a = *(const bf16x8*)&sA[w * 16 + q][8 * g];
#pragma unroll
    for (int t = 0; t < 4; t++) {
      bf16x8 b = *(const bf16x8*)&sB[16 * t + q][8 * g];
      acc[t] = __builtin_amdgcn_mfma_f32_16x16x32_bf16(a, b, acc[t], 0, 0, 0);
    }
    __syncthreads();
  }
  float s = 0.f;
  if (MODE == 3) s = 1.f / (1.f + __expf(-alpha_p[0]));
#pragma unroll
  for (int t = 0; t < 4; t++) {
    int col = bn + 16 * t + q;
#pragma unroll
    for (int rr = 0; rr < 4; rr++) {
      int row = bm + w * 16 + g * 4 + rr;
      if (row < M && col < Nc) {
        float v = acc[t][rr] + bias[col];
        if (MODE == 2) v = v > 0.f ? v : (__expf(v) - 1.f);
        if (MODE == 3) v = s * v + (1.f - s) * aux[(size_t)row * Nc + col];
        if (MODE == 1)
          ((unsigned short*)Cout)[(size_t)row * Nc + col] = f2bf(v);
        else
          ((float*)Cout)[(size_t)row * Nc + col] = v;
      }
    }
  }
}

// ---------------- bf16 MFMA GEMM (batched over grid.z) ----------------
struct GJob { const unsigned short* BT; const float* bias; void* out; int mode; };
struct GJobs { GJob j[3]; };

__global__ __launch_bounds__(256) void gemm_mfma_batched(
    const float* __restrict__ A, GJobs jobs, int M, int K, int Nc) {
  __shared__ unsigned short sA[64][40];
  __shared__ unsigned short sB[64][40];
  GJob jb = jobs.j[blockIdx.z];
  const unsigned short* BT = jb.BT;
  int tid = threadIdx.x, lane = tid & 63, w = tid >> 6;
  int g = lane >> 4, q = lane & 15;
  int bm = blockIdx.y * 64, bn = blockIdx.x * 64;
  f32x4 acc[4];
#pragma unroll
  for (int t = 0; t < 4; t++) acc[t] = (f32x4){0.f, 0.f, 0.f, 0.f};
  int r = tid >> 2, ko = (tid & 3) * 8;
  for (int k0 = 0; k0 < K; k0 += 32) {
    {
      int gm = bm + r;
      bf16x8 v = {};
      if (gm < M) {
        const float* ap = A + (size_t)gm * K + k0 + ko;
        float4 x0 = *(const float4*)ap;
        float4 x1 = *(const float4*)(ap + 4);
        v[0] = (short)f2bf(x0.x); v[1] = (short)f2bf(x0.y);
        v[2] = (short)f2bf(x0.z); v[3] = (short)f2bf(x0.w);
        v[4] = (short)f2bf(x1.x); v[5] = (short)f2bf(x1.y);
        v[6] = (short)f2bf(x1.z); v[7] = (short)f2bf(x1.w);
      }
      *(bf16x8*)&sA[r][ko] = v;
      int gc = bn + r;
      bf16x8 bv = {};
      if (gc < Nc) bv = *(const bf16x8*)(BT + (size_t)gc * K + k0 + ko);
      *(bf16x8*)&sB[r][ko] = bv;
    }
    __syncthreads();
    bf16x8 a = *(const bf16x8*)&sA[w * 16 + q][8 * g];
#pragma unroll
    for (int t = 0; t < 4; t++) {
      bf16x8 b = *(const bf16x8*)&sB[16 * t + q][8 * g];
      acc[t] = __builtin_amdgcn_mfma_f32_16x16x32_bf16(a, b, acc[t], 0, 0, 0);
    }
    __syncthreads();
  }
#pragma unroll
  for (int t = 0; t < 4; t++) {
    int col = bn + 16 * t + q;
#pragma unroll
    for (int rr = 0; rr < 4; rr++) {
      int row = bm + w * 16 + g * 4 + rr;
      if (row < M && col < Nc) {
        float v = acc[t][rr] + jb.bias[col];
        if (jb.mode == 1)
          ((unsigned short*)jb.out)[(size_t)row * Nc + col] = f2bf(v);
        else
          ((float*)jb.out)[(size_t)row * Nc + col] = v;
      }
    }
  }
}

// ---------------- GATv2 edge scores via MFMA; ea_csr read linearly (R18 epilogue) ----------------
template <int C, bool SPLIT>
__global__ __launch_bounds__(256) void score_mfma_kernel(
    const unsigned short* __restrict__ ea_csr, const unsigned short* __restrict__ xl,
    const unsigned short* __restrict__ xr, const float* __restrict__ We,
    const float* __restrict__ att, const int* __restrict__ srcpos,
    const int* __restrict__ dstpos,
    float* __restrict__ e_s, int E2, int HCfull, int col_off_in) {
  int lane = threadIdx.x & 63;
  int wv = threadIdx.x >> 6;
  int g = lane >> 4, q = lane & 15;
  int col_off = SPLIT ? (wv & 1) * 128 : col_off_in;
  bf16x8 bfrag[8][2];
#pragma unroll
  for (int t = 0; t < 8; t++)
#pragma unroll
    for (int kc = 0; kc < 2; kc++) {
      bf16x8 bv;
#pragma unroll
      for (int j = 0; j < 8; j++) {
        int k = kc * 32 + g * 8 + j;
        bv[j] = (short)f2bf(We[(size_t)k * HCfull + col_off + 16 * t + q]);
      }
      bfrag[t][kc] = bv;
    }
  float attv[8];
#pragma unroll
  for (int t = 0; t < 8; t++) attv[t] = att[col_off + 16 * t + q];

  constexpr int TPH = C / 16;
  constexpr int NH = 8 / TPH;
  const int headbase = col_off / C;

  int tiles = (E2 + 15) / 16;
  int tstart = SPLIT ? (blockIdx.x * 2 + (wv >> 1)) : (blockIdx.x * 4 + wv);
  int nw = SPLIT ? (gridDim.x * 2) : (gridDim.x * 4);
  for (int tile = tstart; tile < tiles; tile += nw) {
    int i0 = tile * 16;
    int ia = i0 + q;
    if (ia >= E2) ia = E2 - 1;
    const unsigned short* ap = ea_csr + (size_t)ia * 64 + g * 8;  // linear by CSR position
    bf16x8 a0 = *(const bf16x8*)(ap);
    bf16x8 a1 = *(const bf16x8*)(ap + 32);
    f32x4 acc[8];
#pragma unroll
    for (int t = 0; t < 8; t++) acc[t] = (f32x4){0.f, 0.f, 0.f, 0.f};
#pragma unroll
    for (int t = 0; t < 8; t++) {
      acc[t] = __builtin_amdgcn_mfma_f32_16x16x32_bf16(a0, bfrag[t][0], acc[t], 0, 0, 0);
      acc[t] = __builtin_amdgcn_mfma_f32_16x16x32_bf16(a1, bfrag[t][1], acc[t], 0, 0, 0);
    }
    int sn[4], dn[4];
#pragma unroll
    for (int r = 0; r < 4; r++) {
      int i = i0 + g * 4 + r;
      if (i >= E2) i = E2 - 1;
      sn[r] = srcpos[i];
      dn[r] = dstpos[i];
    }
    float p[NH][4];
#pragma unroll
    for (int hh = 0; hh < NH; hh++)
#pragma unroll
      for (int r = 0; r < 4; r++) p[hh][r] = 0.f;
#pragma unroll
    for (int t = 0; t < 8; t++) {
      int col = col_off + 16 * t + q;
#pragma unroll
      for (int r = 0; r < 4; r++) {
        float xv = bf2f(xl[(size_t)sn[r] * HCfull + col]) +
                   bf2f(xr[(size_t)dn[r] * HCfull + col]) + acc[t][r];
        xv = xv > 0.f ? xv : 0.2f * xv;
        p[t / TPH][r] += xv * attv[t];
      }
    }
#pragma unroll
    for (int hh = 0; hh < NH; hh++)
#pragma unroll
      for (int r = 0; r < 4; r++) {
#pragma unroll
        for (int o = 1; o < 16; o <<= 1) p[hh][r] += __shfl_xor(p[hh][r], o);
      }
    if (q == 0) {
#pragma unroll
      for (int r = 0; r < 4; r++) {
        int i = i0 + g * 4 + r;
        if (i < E2) {
#pragma unroll
          for (int hh = 0; hh < NH; hh++)
            e_s[(size_t)i * 4 + headbase + hh] = p[hh][r];
        }
      }
    }
  }
}

// ---------------- per-node online-softmax + aggregation; 4x-unrolled gather ----------------
template <int HC, bool L1MODE>
__global__ __launch_bounds__(256) void aggr_kernel(
    const float* __restrict__ e_s, const unsigned short* __restrict__ xl,
    const int* __restrict__ rowptr, const int* __restrict__ srcpos,
    const float* __restrict__ bias,
    const float* __restrict__ lng, const float* __restrict__ lnb,
    float* __restrict__ xout,
    float* __restrict__ x1out, const float* __restrict__ skipproj,
    float* __restrict__ md, int N) {
  constexpr int CPL = HC / 64;
  int lane = threadIdx.x & 63, wv = threadIdx.x >> 6;
  int stride = gridDim.x * 4;
  const float4* e_s4 = (const float4*)e_s;
  for (int n = blockIdx.x * 4 + wv; n < N; n += stride) {
    int r0 = rowptr[n], r1 = rowptr[n + 1];
    // single-pass online softmax: running max m and rescaled sum d per head
    float m0 = -1e30f, m1 = -1e30f, m2 = -1e30f, m3 = -1e30f;
    float d0 = 0.f, d1 = 0.f, d2 = 0.f, d3 = 0.f;
    for (int i = r0 + lane; i < r1; i += 64) {
      float4 v = e_s4[i];
      float M;
      M = fmaxf(m0, v.x); d0 = d0 * __expf(m0 - M) + __expf(v.x - M); m0 = M;
      M = fmaxf(m1, v.y); d1 = d1 * __expf(m1 - M) + __expf(v.y - M); m1 = M;
      M = fmaxf(m2, v.z); d2 = d2 * __expf(m2 - M) + __expf(v.z - M); m2 = M;
      M = fmaxf(m3, v.w); d3 = d3 * __expf(m3 - M) + __expf(v.w - M); m3 = M;
    }
#pragma unroll
    for (int o = 1; o < 64; o <<= 1) {
      float mo, dd, M;
      mo = __shfl_xor(m0, o); dd = __shfl_xor(d0, o);
      M = fmaxf(m0, mo); d0 = d0 * __expf(m0 - M) + dd * __expf(mo - M); m0 = M;
      mo = __shfl_xor(m1, o); dd = __shfl_xor(d1, o);
      M = fmaxf(m1, mo); d1 = d1 * __expf(m1 - M) + dd * __expf(mo - M); m1 = M;
      mo = __shfl_xor(m2, o); dd = __shfl_xor(d2, o);
      M = fmaxf(m2, mo); d2 = d2 * __expf(m2 - M) + dd * __expf(mo - M); m2 = M;
      mo = __shfl_xor(m3, o); dd = __shfl_xor(d3, o);
      M = fmaxf(m3, mo); d3 = d3 * __expf(m3 - M) + dd * __expf(mo - M); m3 = M;
    }
    float i0 = 1.f / (d0 + 1e-16f), i1 = 1.f / (d1 + 1e-16f);
    float i2 = 1.f / (d2 + 1e-16f), i3 = 1.f / (d3 + 1e-16f);
    if (lane == 0) {
      float* mp = md + (size_t)n * 8;
      mp[0] = m0; mp[1] = m1; mp[2] = m2; mp[3] = m3;
      mp[4] = i0; mp[5] = i1; mp[6] = i2; mp[7] = i3;
    }
    int h = lane >> 4;
    float mh = (h & 2) ? ((h & 1) ? m3 : m2) : ((h & 1) ? m1 : m0);
    float ih = (h & 2) ? ((h & 1) ? i3 : i2) : ((h & 1) ? i1 : i0);
    float acc[CPL];
#pragma unroll
    for (int j = 0; j < CPL; j++) acc[j] = 0.f;
    int c0 = lane * CPL;
    int i = r0;
    for (; i + 4 <= r1; i += 4) {
      float sh0, sh1, sh2, sh3;
      int sn0, sn1, sn2, sn3;
      {
        float4 a = e_s4[i], b = e_s4[i + 1], c = e_s4[i + 2], d = e_s4[i + 3];
        sh0 = sel4(a, h); sh1 = sel4(b, h); sh2 = sel4(c, h); sh3 = sel4(d, h);
      }
      sn0 = srcpos[i]; sn1 = srcpos[i + 1]; sn2 = srcpos[i + 2]; sn3 = srcpos[i + 3];
      if constexpr (CPL == 2) {
        ushort2 t0 = *(const ushort2*)(xl + (size_t)sn0 * HC + c0);
        ushort2 t1 = *(const ushort2*)(xl + (size_t)sn1 * HC + c0);
        ushort2 t2 = *(const ushort2*)(xl + (size_t)sn2 * HC + c0);
        ushort2 t3 = *(const ushort2*)(xl + (size_t)sn3 * HC + c0);
        float a0 = __expf(sh0 - mh) * ih;
        float a1 = __expf(sh1 - mh) * ih;
        float a2 = __expf(sh2 - mh) * ih;
        float a3 = __expf(sh3 - mh) * ih;
        acc[0] += a0 * bf2f(t0.x) + a1 * bf2f(t1.x) + a2 * bf2f(t2.x) + a3 * bf2f(t3.x);
        acc[1] += a0 * bf2f(t0.y) + a1 * bf2f(t1.y) + a2 * bf2f(t2.y) + a3 * bf2f(t3.y);
      } else {
        ushort4 t0 = *(const ushort4*)(xl + (size_t)sn0 * HC + c0);
        ushort4 t1 = *(const ushort4*)(xl + (size_t)sn1 * HC + c0);
        ushort4 t2 = *(const ushort4*)(xl + (size_t)sn2 * HC + c0);
        ushort4 t3 = *(const ushort4*)(xl + (size_t)sn3 * HC + c0);
        float a0 = __expf(sh0 - mh) * ih;
        float a1 = __expf(sh1 - mh) * ih;
        float a2 = __expf(sh2 - mh) * ih;
        float a3 = __expf(sh3 - mh) * ih;
        acc[0] += a0 * bf2f(t0.x) + a1 * bf2f(t1.x) + a2 * bf2f(t2.x) + a3 * bf2f(t3.x);
        acc[1] += a0 * bf2f(t0.y) + a1 * bf2f(t1.y) + a2 * bf2f(t2.y) + a3 * bf2f(t3.y);
        acc[2] += a0 * bf2f(t0.z) + a1 * bf2f(t1.z) + a2 * bf2f(t2.z) + a3 * bf2f(t3.z);
        acc[3] += a0 * bf2f(t0.w) + a1 * bf2f(t1.w) + a2 * bf2f(t2.w) + a3 * bf2f(t3.w);
      }
    }
    for (; i < r1; i++) {
      float sh = sel4(e_s4[i], h);
      float a = __expf(sh - mh) * ih;
      int sn = srcpos[i];
      const unsigned short* xp = xl + (size_t)sn * HC + c0;
      if constexpr (CPL == 2) {
        ushort2 t = *(const ushort2*)xp;
        acc[0] += a * bf2f(t.x);
        acc[1] += a * bf2f(t.y);
      } else {
        ushort4 t = *(const ushort4*)xp;
        acc[0] += a * bf2f(t.x);
        acc[1] += a * bf2f(t.y);
        acc[2] += a * bf2f(t.z);
        acc[3] += a * bf2f(t.w);
      }
    }
    float vals[CPL];
    float vs = 0.f, vq = 0.f;
#pragma unroll
    for (int j = 0; j < CPL; j++) {
      float t = acc[j] + bias[c0 + j];
      vals[j] = t;
      vs += t;
      vq += t * t;
    }
    vs = wave_sum(vs);
    vq = wave_sum(vq);
    float mean = vs * (1.f / HC);
    float var = vq * (1.f / HC) - mean * mean;
    float rstd = rsqrtf(fmaxf(var, 0.f) + 1e-5f);
#pragma unroll
    for (int j = 0; j < CPL; j++) {
      int c = c0 + j;
      float y = (vals[j] - mean) * rstd * lng[c] + lnb[c];
      y = leakyf(y, 0.01f);
      if constexpr (L1MODE) {
        x1out[(size_t)n * HC + c] = y;
        xout[(size_t)n * HC + c] = 0.01f * skipproj[(size_t)n * HC + c] + y;
      } else {
        xout[(size_t)n * HC + c] = y;
      }
    }
  }
}

// ---------------- alpha: coalesced e_s/dstpos read, md L2-hit, one scattered 16B write ----------------
__global__ __launch_bounds__(256) void alpha_kernel(
    const float* __restrict__ e_s, const int* __restrict__ csr,
    const int* __restrict__ dstpos, const float* __restrict__ md,
    float* __restrict__ alpha_out, int E2) {
  int i = blockIdx.x * 256 + threadIdx.x;
  if (i < E2) {
    float4 sv = ((const float4*)e_s)[i];
    int d = dstpos[i];
    const float* mp = md + (size_t)d * 8;
    float4 a;
    a.x = __expf(sv.x - mp[0]) * mp[4];
    a.y = __expf(sv.y - mp[1]) * mp[5];
    a.z = __expf(sv.z - mp[2]) * mp[6];
    a.w = __expf(sv.w - mp[3]) * mp[7];
    ((float4*)alpha_out)[csr[i]] = a;
  }
}

extern "C" void kernel_launch(void* const* d_in, const int* in_sizes, int n_in,
                              void* d_out, int out_size, void* d_ws, size_t ws_size,
                              hipStream_t stream) {
  (void)n_in;
  (void)out_size;
  (void)ws_size;
  const float* x_in = (const float*)d_in[0];
  const int* edge_index = (const int*)d_in[1];
  const float* edge_attr = (const float*)d_in[2];
  const float* bn0_g = (const float*)d_in[3];
  const float* bn0_b = (const float*)d_in[4];
  const float* bn0_m = (const float*)d_in[5];
  const float* bn0_v = (const float*)d_in[6];
  const float* eeW1 = (const float*)d_in[7];
  const float* eeb1 = (const float*)d_in[8];
  const float* eeW2 = (const float*)d_in[9];
  const float* eeb2 = (const float*)d_in[10];
  const float* g1_Wl = (const float*)d_in[11];
  const float* g1_bl = (const float*)d_in[12];
  const float* g1_Wr = (const float*)d_in[13];
  const float* g1_br = (const float*)d_in[14];
  const float* g1_We = (const float*)d_in[15];
  const float* g1_att = (const float*)d_in[16];
  const float* g1_bias = (const float*)d_in[17];
  const float* g2_Wl = (const float*)d_in[18];
  const float* g2_bl = (const float*)d_in[19];
  const float* g2_Wr = (const float*)d_in[20];
  const float* g2_br = (const float*)d_in[21];
  const float* g2_We = (const float*)d_in[22];
  const float* g2_att = (const float*)d_in[23];
  const float* g2_bias = (const float*)d_in[24];
  const float* g3_Wl = (const float*)d_in[25];
  const float* g3_bl = (const float*)d_in[26];
  const float* g3_Wr = (const float*)d_in[27];
  const float* g3_br = (const float*)d_in[28];
  const float* g3_We = (const float*)d_in[29];
  const float* g3_att = (const float*)d_in[30];
  const float* g3_bias = (const float*)d_in[31];
  const float* ln1_g = (const float*)d_in[32];
  const float* ln1_b = (const float*)d_in[33];
  const float* ln2_g = (const float*)d_in[34];
  const float* ln2_b = (const float*)d_in[35];
  const float* ln3_g = (const float*)d_in[36];
  const float* ln3_b = (const float*)d_in[37];
  const float* skip_W = (const float*)d_in[38];
  const float* skip_b = (const float*)d_in[39];
  const float* alpha_p = (const float*)d_in[40];
  const float* fp_W = (const float*)d_in[41];
  const float* fp_b = (const float*)d_in[42];
  const float* np_W1 = (const float*)d_in[43];
  const float* np_b1 = (const float*)d_in[44];
  const float* np_W2 = (const float*)d_in[45];
  const float* np_b2 = (const float*)d_in[46];
  const float* np_W3 = (const float*)d_in[47];
  const float* np_b3 = (const float*)d_in[48];

  const int N = in_sizes[0] / 64;
  const int E = in_sizes[2] / 16;
  const int E2 = E + N;
  const int* src0 = edge_index;
  const int* dst0 = edge_index + E;

  float* ws = (float*)d_ws;
  size_t off = 0;
  float* x = ws + off;         off += (size_t)N * 64;
  unsigned short* ea_csr = (unsigned short*)(ws + off); off += (size_t)E2 * 32;
  unsigned short* xl = (unsigned short*)(ws + off);    off += (size_t)N * 128;
  unsigned short* xr = (unsigned short*)(ws + off);    off += (size_t)N * 128;
  float* skipproj = ws + off;  off += (size_t)N * 128;  // reused as h1 at the end
  float* x1 = ws + off;        off += (size_t)N * 128;
  float* skip1 = ws + off;     off += (size_t)N * 128;
  float* x2 = ws + off;        off += (size_t)N * 128;
  float* x3 = ws + off;        off += (size_t)N * 256;
  float* e_s = ws + off;       off += (size_t)E2 * 4;
  float* h2 = ws + off;        off += (size_t)N * 64;
  float* md = ws + off;        off += (size_t)N * 8;
  int* counts = (int*)(ws + off);
  int* rowptr = counts + N;
  int* fill = rowptr + N + 1;
  int* csr = fill + N;
  int* srcpos = csr + E2;
  int* dstpos = srcpos + E2;
  int* inv = dstpos + E2;
  off += (size_t)(3 * N + 1 + 4 * E2);
  off = (off + 3) & ~(size_t)3;
  unsigned short* wtp = (unsigned short*)(ws + off);
  auto alloc_wt = [&](int elems) {
    unsigned short* p = wtp;
    wtp += (elems + 7) & ~7;
    return p;
  };
  unsigned short* wt_g1l = alloc_wt(64 * 128);
  unsigned short* wt_g1r = alloc_wt(64 * 128);
  unsigned short* wt_skip = alloc_wt(64 * 128);
  unsigned short* wt_g2l = alloc_wt(128 * 128);
  unsigned short* wt_g2r = alloc_wt(128 * 128);
  unsigned short* wt_g3l = alloc_wt(128 * 256);
  unsigned short* wt_g3r = alloc_wt(128 * 256);
  unsigned short* wt_fp = alloc_wt(128 * 256);
  unsigned short* wt_np1 = alloc_wt(256 * 128);
  unsigned short* wt_np2 = alloc_wt(128 * 64);
  unsigned short* wt_np3 = alloc_wt(64 * 1);
  unsigned short* wt_ee1 = alloc_wt(16 * 128);
  unsigned short* wt_ee2 = alloc_wt(128 * 64);

  float* out = (float*)d_out;
  float* xf = out;
  float* npout = out + (size_t)N * 256;
  float* a1 = npout + N;
  float* a2 = a1 + (size_t)E2 * 4;
  float* a3 = a2 + (size_t)E2 * 4;

  WJobs jobs;
  jobs.j[0] = {g1_Wl, wt_g1l, 64, 128};
  jobs.j[1] = {g1_Wr, wt_g1r, 64, 128};
  jobs.j[2] = {skip_W, wt_skip, 64, 128};
  jobs.j[3] = {g2_Wl, wt_g2l, 128, 128};
  jobs.j[4] = {g2_Wr, wt_g2r, 128, 128};
  jobs.j[5] = {g3_Wl, wt_g3l, 128, 256};
  jobs.j[6] = {g3_Wr, wt_g3r, 128, 256};
  jobs.j[7] = {fp_W, wt_fp, 128, 256};
  jobs.j[8] = {np_W1, wt_np1, 256, 128};
  jobs.j[9] = {np_W2, wt_np2, 128, 64};
  jobs.j[10] = {np_W3, wt_np3, 64, 1};
  jobs.j[11] = {eeW1, wt_ee1, 16, 128};
  jobs.j[12] = {eeW2, wt_ee2, 128, 64};

  hipMemsetAsync(counts, 0, (size_t)N * sizeof(int), stream);
  wt_kernel<<<dim3(64, 13), 256, 0, stream>>>(jobs);
  bn_kernel<<<(N * 64 + 255) / 256, 256, 0, stream>>>(x_in, bn0_g, bn0_b, bn0_m, bn0_v, x, N * 64);
  count_kernel<<<(E2 + 255) / 256, 256, 0, stream>>>(dst0, counts, E, E2);
  scan_kernel<<<1, 1024, 0, stream>>>(counts, rowptr, fill, N);
  fill_kernel<<<(E2 + 255) / 256, 256, 0, stream>>>(src0, dst0, fill, csr, srcpos, dstpos, inv, E, E2);
  edge_enc_kernel<<<1280, 256, 0, stream>>>(edge_attr, wt_ee1, eeb1, wt_ee2, eeb2, ea_csr, inv, E);
  loopattr_kernel<<<(N + 3) / 4, 256, 0, stream>>>(ea_csr, rowptr, csr, N, E);

  auto gemm = [&](int mode, const float* A, const unsigned short* BT, const float* bias,
                  void* Cp, int M, int K, int Nc, const float* aux) {
    dim3 gdim((Nc + 63) / 64, (M + 63) / 64);
    switch (mode) {
      case 0: gemm_mfma_kernel<0><<<gdim, 256, 0, stream>>>(A, BT, bias, Cp, M, K, Nc, nullptr, nullptr); break;
      case 2: gemm_mfma_kernel<2><<<gdim, 256, 0, stream>>>(A, BT, bias, Cp, M, K, Nc, nullptr, nullptr); break;
      case 3: gemm_mfma_kernel<3><<<gdim, 256, 0, stream>>>(A, BT, bias, Cp, M, K, Nc, aux, alpha_p); break;
    }
  };
  auto gemm_batch = [&](const float* A, int M, int K, int Nc, GJobs gj, int nz) {
    dim3 gdim((Nc + 63) / 64, (M + 63) / 64, nz);
    gemm_mfma_batched<<<gdim, 256, 0, stream>>>(A, gj, M, K, Nc);
  };

  const int nblk_node = (N + 3) / 4;
  const int score_blocks = 1024;
  const int nblk_edge = (E2 + 255) / 256;

  // ---- Layer 1 (din=64, HC=128, C=32) ----
  {
    GJobs gj;
    gj.j[0] = {wt_g1l, g1_bl, xl, 1};
    gj.j[1] = {wt_g1r, g1_br, xr, 1};
    gj.j[2] = {wt_skip, skip_b, skipproj, 0};
    gemm_batch(x, N, 64, 128, gj, 3);
  }
  score_mfma_kernel<32, false><<<score_blocks, 256, 0, stream>>>(ea_csr, xl, xr, g1_We, g1_att, srcpos, dstpos, e_s, E2, 128, 0);
  aggr_kernel<128, true><<<nblk_node, 256, 0, stream>>>(e_s, xl, rowptr, srcpos, g1_bias, ln1_g, ln1_b,
                                                        skip1, x1, skipproj, md, N);
  alpha_kernel<<<nblk_edge, 256, 0, stream>>>(e_s, csr, dstpos, md, a1, E2);
  // ---- Layer 2 (din=128, HC=128, C=32) ----
  {
    GJobs gj;
    gj.j[0] = {wt_g2l, g2_bl, xl, 1};
    gj.j[1] = {wt_g2r, g2_br, xr, 1};
    gj.j[2] = {nullptr, nullptr, nullptr, 0};
    gemm_batch(skip1, N, 128, 128, gj, 2);
  }
  score_mfma_kernel<32, false><<<score_blocks, 256, 0, stream>>>(ea_csr, xl, xr, g2_We, g2_att, srcpos, dstpos, e_s, E2, 128, 0);
  aggr_kernel<128, false><<<nblk_node, 256, 0, stream>>>(e_s, xl, rowptr, srcpos, g2_bias, ln2_g, ln2_b,
                                                         x2, nullptr, nullptr, md, N);
  alpha_kernel<<<nblk_edge, 256, 0, stream>>>(e_s, csr, dstpos, md, a2, E2);
  // ---- Layer 3 (din=128, HC=256, C=64): one launch, wave-split col halves ----
  {
    GJobs gj;
    gj.j[0] = {wt_g3l, g3_bl, xl, 1};
    gj.j[1] = {wt_g3r, g3_br, xr, 1};
    gj.j[2] = {nullptr, nullptr, nullptr, 0};
    gemm_batch(x2, N, 128, 256, gj, 2);
  }
  score_mfma_kernel<64, true><<<score_blocks, 256, 0, stream>>>(ea_csr, xl, xr, g3_We, g3_att, srcpos, dstpos, e_s, E2, 256, 0);
  aggr_kernel<256, false><<<nblk_node, 256, 0, stream>>>(e_s, xl, rowptr, srcpos, g3_bias, ln3_g, ln3_b,
                                                         x3, nullptr, nullptr, md, N);
  alpha_kernel<<<nblk_edge, 256, 0, stream>>>(e_s, csr, dstpos, md, a3, E2);
  // ---- Final: xf = s*(x1@fp_W+fp_b) + (1-s)*x3 ; node MLP ----
  gemm(3, x1, wt_fp, fp_b, xf, N, 128, 256, x3);
  gemm(2, xf, wt_np1, np_b1, skipproj, N, 256, 128, nullptr);   // h1
  gemm(2, skipproj, wt_np2, np_b2, h2, N, 128, 64, nullptr);    // h2
  gemm(0, h2, wt_np3, np_b3, npout, N, 64, 1, nullptr);
}

// Round 23
// 506.351 us; speedup vs baseline: 1.0449x; 1.0086x over previous
//
#include <hip/hip_runtime.h>
#include <math.h>

#define DEV __device__ __forceinline__

typedef __attribute__((ext_vector_type(8))) short bf16x8;
typedef __attribute__((ext_vector_type(4))) float f32x4;

DEV float leakyf(float x, float s) { return x > 0.f ? x : s * x; }

DEV unsigned short f2bf(float f) {
  unsigned u = __float_as_uint(f);
  unsigned r = (u + 0x7fff + ((u >> 16) & 1)) >> 16;
  return (unsigned short)r;
}
DEV float bf2f(unsigned short h) { return __uint_as_float((unsigned)h << 16); }

DEV float sel4(float4 v, int h) {
  float a = (h & 1) ? v.y : v.x;
  float b = (h & 1) ? v.w : v.z;
  return (h & 2) ? b : a;
}

DEV float wave_sum(float v) {
#pragma unroll
  for (int o = 1; o < 64; o <<= 1) v += __shfl_xor(v, o);
  return v;
}
DEV float wave_max(float v) {
#pragma unroll
  for (int o = 1; o < 64; o <<= 1) v = fmaxf(v, __shfl_xor(v, o));
  return v;
}

// ---------------- weight pre-convert: W[K,Nc] f32 -> WT[Nc,K] bf16 ----------------
struct WJob { const float* in; unsigned short* out; int K; int Nc; };
struct WJobs { WJob j[13]; };

__global__ __launch_bounds__(256) void wt_kernel(WJobs jobs) {
  WJob jb = jobs.j[blockIdx.y];
  int total = jb.K * jb.Nc;
  for (int i = blockIdx.x * 256 + threadIdx.x; i < total; i += gridDim.x * 256) {
    int c = i / jb.K, k = i - c * jb.K;
    jb.out[i] = f2bf(jb.in[(size_t)k * jb.Nc + c]);
  }
}

// ---------------- BatchNorm (eval) ----------------
__global__ __launch_bounds__(256) void bn_kernel(
    const float* __restrict__ xin, const float* __restrict__ g,
    const float* __restrict__ b, const float* __restrict__ m,
    const float* __restrict__ v, float* __restrict__ xout, int total) {
  int i = blockIdx.x * 256 + threadIdx.x;
  if (i < total) {
    int c = i & 63;
    xout[i] = (xin[i] - m[c]) * rsqrtf(v[c] + 1e-5f) * g[c] + b[c];
  }
}

// ---------------- Edge encoder: fully-MFMA, persistent; writes rows into CSR order via inv[] ----------------
__global__ __launch_bounds__(256, 2) void edge_enc_kernel(
    const float* __restrict__ edge_attr, const unsigned short* __restrict__ WT1,
    const float* __restrict__ b1, const unsigned short* __restrict__ WT2,
    const float* __restrict__ b2, unsigned short* __restrict__ ea_csr,
    const int* __restrict__ inv, int E) {
  __shared__ unsigned short sEa1[64][136];  // bf16, pad 8
  int tid = threadIdx.x, lane = tid & 63, w = tid >> 6;
  int g = lane >> 4, q = lane & 15;
  bf16x8 w1f[8];
#pragma unroll
  for (int t = 0; t < 8; t++) {
    bf16x8 v = {};
    if (g < 2) v = *(const bf16x8*)(WT1 + (size_t)(16 * t + q) * 16 + 8 * g);
    w1f[t] = v;
  }
  float b1v[8];
#pragma unroll
  for (int t = 0; t < 8; t++) b1v[t] = b1[16 * t + q];
  bf16x8 w2f[4][4];
#pragma unroll
  for (int t = 0; t < 4; t++)
#pragma unroll
    for (int kc = 0; kc < 4; kc++)
      w2f[t][kc] = *(const bf16x8*)(WT2 + (size_t)(16 * t + q) * 128 + 32 * kc + 8 * g);
  float b2v[4];
#pragma unroll
  for (int t = 0; t < 4; t++) b2v[t] = b2[16 * t + q];

  int gstride = gridDim.x * 64;

  auto load_attr = [&](int base) -> bf16x8 {
    bf16x8 af = {};
    if (g < 2) {
      int e = base + w * 16 + q;
      if (e >= E) e = E - 1;
      const float* ap = edge_attr + (size_t)e * 16 + 8 * g;
      float4 x0 = *(const float4*)ap;
      float4 x1 = *(const float4*)(ap + 4);
      af[0] = (short)f2bf(x0.x); af[1] = (short)f2bf(x0.y);
      af[2] = (short)f2bf(x0.z); af[3] = (short)f2bf(x0.w);
      af[4] = (short)f2bf(x1.x); af[5] = (short)f2bf(x1.y);
      af[6] = (short)f2bf(x1.z); af[7] = (short)f2bf(x1.w);
    }
    return af;
  };

  int base = blockIdx.x * 64;
  if (base >= E) return;
  bf16x8 af = load_attr(base);
  for (; base < E; ) {
    int next = base + gstride;
    bf16x8 af_next = {};
    if (next < E) af_next = load_attr(next);  // prefetch overlaps with compute below
    int e0 = base + w * 16;
    f32x4 acc1[8];
#pragma unroll
    for (int t = 0; t < 8; t++) acc1[t] = (f32x4){0.f, 0.f, 0.f, 0.f};
#pragma unroll
    for (int t = 0; t < 8; t++)
      acc1[t] = __builtin_amdgcn_mfma_f32_16x16x32_bf16(af, w1f[t], acc1[t], 0, 0, 0);
#pragma unroll
    for (int t = 0; t < 8; t++)
#pragma unroll
      for (int r = 0; r < 4; r++) {
        float v = leakyf(acc1[t][r] + b1v[t], 0.01f);
        sEa1[w * 16 + g * 4 + r][16 * t + q] = f2bf(v);
      }
    f32x4 acc2[4];
#pragma unroll
    for (int t = 0; t < 4; t++) acc2[t] = (f32x4){0.f, 0.f, 0.f, 0.f};
#pragma unroll
    for (int kc = 0; kc < 4; kc++) {
      bf16x8 a2 = *(const bf16x8*)&sEa1[w * 16 + q][32 * kc + 8 * g];
#pragma unroll
      for (int t = 0; t < 4; t++)
        acc2[t] = __builtin_amdgcn_mfma_f32_16x16x32_bf16(a2, w2f[t][kc], acc2[t], 0, 0, 0);
    }
#pragma unroll
    for (int r = 0; r < 4; r++) {
      float vv[4];
      float p = 0.f;
#pragma unroll
      for (int t = 0; t < 4; t++) {
        float v = leakyf(acc2[t][r] + b2v[t], 0.01f);
        vv[t] = v;
        p += v * v;
      }
#pragma unroll
      for (int o = 1; o < 16; o <<= 1) p += __shfl_xor(p, o);
      float sc = 1.f / fmaxf(sqrtf(p), 1e-12f);
      int e = e0 + g * 4 + r;
      if (e < E) {
        int pos = inv[e];  // CSR position of this edge
#pragma unroll
        for (int t = 0; t < 4; t++)
          ea_csr[(size_t)pos * 64 + 16 * t + q] = f2bf(vv[t] * sc);
      }
    }
    af = af_next;
    base = next;
  }
}

// ---------------- CSR build ----------------
__global__ __launch_bounds__(256) void count_kernel(const int* __restrict__ dst0,
                                                    int* __restrict__ counts, int E, int E2) {
  int i = blockIdx.x * 256 + threadIdx.x;
  if (i < E2) {
    int d = (i < E) ? dst0[i] : (i - E);
    atomicAdd(&counts[d], 1);
  }
}

// 1024-thread block scan
__global__ __launch_bounds__(1024) void scan_kernel(const int* __restrict__ counts,
                                                    int* __restrict__ rowptr,
                                                    int* __restrict__ fill, int N) {
  __shared__ int part[1024];
  int tid = threadIdx.x;
  int chunk = (N + 1023) / 1024;
  int lo = tid * chunk, hi = lo + chunk;
  if (hi > N) hi = N;
  if (lo > N) lo = N;
  int s = 0;
  for (int i = lo; i < hi; i++) s += counts[i];
  part[tid] = s;
  __syncthreads();
#pragma unroll
  for (int o = 1; o < 1024; o <<= 1) {
    int v = (tid >= o) ? part[tid - o] : 0;
    __syncthreads();
    part[tid] += v;
    __syncthreads();
  }
  if (tid == 1023) rowptr[N] = part[1023];
  int off = part[tid] - s;  // exclusive prefix
  for (int i = lo; i < hi; i++) {
    rowptr[i] = off;
    fill[i] = off;
    off += counts[i];
  }
}

// builds csr (edge id), srcpos, dstpos by CSR position; inv (edge -> position)
__global__ __launch_bounds__(256) void fill_kernel(const int* __restrict__ src0,
                                                   const int* __restrict__ dst0,
                                                   int* __restrict__ fill,
                                                   int* __restrict__ csr,
                                                   int* __restrict__ srcpos,
                                                   int* __restrict__ dstpos,
                                                   int* __restrict__ inv, int E, int E2) {
  int i = blockIdx.x * 256 + threadIdx.x;
  if (i < E2) {
    int d, s;
    if (i < E) {
      d = dst0[i];
      s = src0[i];
    } else {
      d = s = i - E;
    }
    int pos = atomicAdd(&fill[d], 1);
    csr[pos] = i;
    srcpos[pos] = s;
    dstpos[pos] = d;
    inv[i] = pos;
  }
}

// ---------------- self-loop attr = mean of incoming encoded attrs (CSR-linear) ----------------
__global__ __launch_bounds__(256) void loopattr_kernel(unsigned short* __restrict__ ea_csr,
                                                       const int* __restrict__ rowptr,
                                                       const int* __restrict__ csr, int N, int E) {
  int lane = threadIdx.x & 63, wv = threadIdx.x >> 6;
  int stride = gridDim.x * 4;
  for (int n = blockIdx.x * 4 + wv; n < N; n += stride) {
    int r0 = rowptr[n], r1 = rowptr[n + 1];
    float acc = 0.f;
    int loop_pos = r0;
    for (int i = r0; i < r1; i++) {
      int e = csr[i];
      if (e < E) {
        acc += bf2f(ea_csr[(size_t)i * 64 + lane]);  // linear row read
      } else {
        loop_pos = i;
      }
    }
    int cnt = r1 - r0 - 1;  // real incoming edges (exactly one self-loop per node)
    ea_csr[(size_t)loop_pos * 64 + lane] = f2bf(acc / fmaxf((float)cnt, 1.f));
  }
}

// ---------------- bf16 MFMA GEMM (single) ----------------
// MODE: 0 f32 out, 1 bf16 out, 2 elu f32 out, 3 mix f32 out
template <int MODE>
__global__ __launch_bounds__(256) void gemm_mfma_kernel(
    const float* __restrict__ A, const unsigned short* __restrict__ BT,
    const float* __restrict__ bias, void* __restrict__ Cout, int M, int K, int Nc,
    const float* __restrict__ aux, const float* __restrict__ alpha_p) {
  __shared__ unsigned short sA[64][40];
  __shared__ unsigned short sB[64][40];
  int tid = threadIdx.x, lane = tid & 63, w = tid >> 6;
  int g = lane >> 4, q = lane & 15;
  int bm = blockIdx.y * 64, bn = blockIdx.x * 64;
  f32x4 acc[4];
#pragma unroll
  for (int t = 0; t < 4; t++) acc[t] = (f32x4){0.f, 0.f, 0.f, 0.f};
  int r = tid >> 2, ko = (tid & 3) * 8;
  for (int k0 = 0; k0 < K; k0 += 32) {
    {
      int gm = bm + r;
      bf16x8 v = {};
      if (gm < M) {
        const float* ap = A + (size_t)gm * K + k0 + ko;
        float4 x0 = *(const float4*)ap;
        float4 x1 = *(const float4*)(ap + 4);
        v[0] = (short)f2bf(x0.x); v[1] = (short)f2bf(x0.y);
        v[2] = (short)f2bf(x0.z); v[3] = (short)f2bf(x0.w);
        v[4] = (short)f2bf(x1.x); v[5] = (short)f2bf(x1.y);
        v[6] = (short)f2bf(x1.z); v[7] = (short)f2bf(x1.w);
      }
      *(bf16x8*)&sA[r][ko] = v;
      int gc = bn + r;
      bf16x8 bv = {};
      if (gc < Nc) bv = *(const bf16x8*)(BT + (size_t)gc * K + k0 + ko);
      *(bf16x8*)&sB[r][ko] = bv;
    }
    __syncthreads();
    bf16x8 a = *(const bf16x8*)&sA[w * 16 + q][8 * g];
#pragma unroll
    for (int t = 0; t < 4; t++) {
      bf16x8 b = *(const bf16x8*)&sB[16 * t + q][8 * g];
      acc[t] = __builtin_amdgcn_mfma_f32_16x16x32_bf16(a, b, acc[t], 0, 0, 0);
    }
    __syncthreads();
  }
  float s = 0.f;
  if (MODE == 3) s = 1.f / (1.f + __expf(-alpha_p[0]));
#pragma unroll
  for (int t = 0; t < 4; t++) {
    int col = bn + 16 * t + q;
#pragma unroll
    for (int rr = 0; rr < 4; rr++) {
      int row = bm + w * 16 + g * 4 + rr;
      if (row < M && col < Nc) {
        float v = acc[t][rr] + bias[col];
        if (MODE == 2) v = v > 0.f ? v : (__expf(v) - 1.f);
        if (MODE == 3) v = s * v + (1.f - s) * aux[(size_t)row * Nc + col];
        if (MODE == 1)
          ((unsigned short*)Cout)[(size_t)row * Nc + col] = f2bf(v);
        else
          ((float*)Cout)[(size_t)row * Nc + col] = v;
      }
    }
  }
}

// ---------------- bf16 MFMA GEMM (batched over grid.z) ----------------
struct GJob { const unsigned short* BT; const float* bias; void* out; int mode; };
struct GJobs { GJob j[3]; };

__global__ __launch_bounds__(256) void gemm_mfma_batched(
    const float* __restrict__ A, GJobs jobs, int M, int K, int Nc) {
  __shared__ unsigned short sA[64][40];
  __shared__ unsigned short sB[64][40];
  GJob jb = jobs.j[blockIdx.z];
  const unsigned short* BT = jb.BT;
  int tid = threadIdx.x, lane = tid & 63, w = tid >> 6;
  int g = lane >> 4, q = lane & 15;
  int bm = blockIdx.y * 64, bn = blockIdx.x * 64;
  f32x4 acc[4];
#pragma unroll
  for (int t = 0; t < 4; t++) acc[t] = (f32x4){0.f, 0.f, 0.f, 0.f};
  int r = tid >> 2, ko = (tid & 3) * 8;
  for (int k0 = 0; k0 < K; k0 += 32) {
    {
      int gm = bm + r;
      bf16x8 v = {};
      if (gm < M) {
        const float* ap = A + (size_t)gm * K + k0 + ko;
        float4 x0 = *(const float4*)ap;
        float4 x1 = *(const float4*)(ap + 4);
        v[0] = (short)f2bf(x0.x); v[1] = (short)f2bf(x0.y);
        v[2] = (short)f2bf(x0.z); v[3] = (short)f2bf(x0.w);
        v[4] = (short)f2bf(x1.x); v[5] = (short)f2bf(x1.y);
        v[6] = (short)f2bf(x1.z); v[7] = (short)f2bf(x1.w);
      }
      *(bf16x8*)&sA[r][ko] = v;
      int gc = bn + r;
      bf16x8 bv = {};
      if (gc < Nc) bv = *(const bf16x8*)(BT + (size_t)gc * K + k0 + ko);
      *(bf16x8*)&sB[r][ko] = bv;
    }
    __syncthreads();
    bf16x8 a = *(const bf16x8*)&sA[w * 16 + q][8 * g];
#pragma unroll
    for (int t = 0; t < 4; t++) {
      bf16x8 b = *(const bf16x8*)&sB[16 * t + q][8 * g];
      acc[t] = __builtin_amdgcn_mfma_f32_16x16x32_bf16(a, b, acc[t], 0, 0, 0);
    }
    __syncthreads();
  }
#pragma unroll
  for (int t = 0; t < 4; t++) {
    int col = bn + 16 * t + q;
#pragma unroll
    for (int rr = 0; rr < 4; rr++) {
      int row = bm + w * 16 + g * 4 + rr;
      if (row < M && col < Nc) {
        float v = acc[t][rr] + jb.bias[col];
        if (jb.mode == 1)
          ((unsigned short*)jb.out)[(size_t)row * Nc + col] = f2bf(v);
        else
          ((float*)jb.out)[(size_t)row * Nc + col] = v;
      }
    }
  }
}

// ---------------- GATv2 edge scores via MFMA; ea_csr read linearly (R18 epilogue) ----------------
template <int C, bool SPLIT>
__global__ __launch_bounds__(256) void score_mfma_kernel(
    const unsigned short* __restrict__ ea_csr, const unsigned short* __restrict__ xl,
    const unsigned short* __restrict__ xr, const float* __restrict__ We,
    const float* __restrict__ att, const int* __restrict__ srcpos,
    const int* __restrict__ dstpos,
    float* __restrict__ e_s, int E2, int HCfull, int col_off_in) {
  int lane = threadIdx.x & 63;
  int wv = threadIdx.x >> 6;
  int g = lane >> 4, q = lane & 15;
  int col_off = SPLIT ? (wv & 1) * 128 : col_off_in;
  bf16x8 bfrag[8][2];
#pragma unroll
  for (int t = 0; t < 8; t++)
#pragma unroll
    for (int kc = 0; kc < 2; kc++) {
      bf16x8 bv;
#pragma unroll
      for (int j = 0; j < 8; j++) {
        int k = kc * 32 + g * 8 + j;
        bv[j] = (short)f2bf(We[(size_t)k * HCfull + col_off + 16 * t + q]);
      }
      bfrag[t][kc] = bv;
    }
  float attv[8];
#pragma unroll
  for (int t = 0; t < 8; t++) attv[t] = att[col_off + 16 * t + q];

  constexpr int TPH = C / 16;
  constexpr int NH = 8 / TPH;
  const int headbase = col_off / C;

  int tiles = (E2 + 15) / 16;
  int tstart = SPLIT ? (blockIdx.x * 2 + (wv >> 1)) : (blockIdx.x * 4 + wv);
  int nw = SPLIT ? (gridDim.x * 2) : (gridDim.x * 4);
  for (int tile = tstart; tile < tiles; tile += nw) {
    int i0 = tile * 16;
    int ia = i0 + q;
    if (ia >= E2) ia = E2 - 1;
    const unsigned short* ap = ea_csr + (size_t)ia * 64 + g * 8;  // linear by CSR position
    bf16x8 a0 = *(const bf16x8*)(ap);
    bf16x8 a1 = *(const bf16x8*)(ap + 32);
    f32x4 acc[8];
#pragma unroll
    for (int t = 0; t < 8; t++) acc[t] = (f32x4){0.f, 0.f, 0.f, 0.f};
#pragma unroll
    for (int t = 0; t < 8; t++) {
      acc[t] = __builtin_amdgcn_mfma_f32_16x16x32_bf16(a0, bfrag[t][0], acc[t], 0, 0, 0);
      acc[t] = __builtin_amdgcn_mfma_f32_16x16x32_bf16(a1, bfrag[t][1], acc[t], 0, 0, 0);
    }
    int sn[4], dn[4];
#pragma unroll
    for (int r = 0; r < 4; r++) {
      int i = i0 + g * 4 + r;
      if (i >= E2) i = E2 - 1;
      sn[r] = srcpos[i];
      dn[r] = dstpos[i];
    }
    float p[NH][4];
#pragma unroll
    for (int hh = 0; hh < NH; hh++)
#pragma unroll
      for (int r = 0; r < 4; r++) p[hh][r] = 0.f;
#pragma unroll
    for (int t = 0; t < 8; t++) {
      int col = col_off + 16 * t + q;
#pragma unroll
      for (int r = 0; r < 4; r++) {
        float xv = bf2f(xl[(size_t)sn[r] * HCfull + col]) +
                   bf2f(xr[(size_t)dn[r] * HCfull + col]) + acc[t][r];
        xv = xv > 0.f ? xv : 0.2f * xv;
        p[t / TPH][r] += xv * attv[t];
      }
    }
#pragma unroll
    for (int hh = 0; hh < NH; hh++)
#pragma unroll
      for (int r = 0; r < 4; r++) {
#pragma unroll
        for (int o = 1; o < 16; o <<= 1) p[hh][r] += __shfl_xor(p[hh][r], o);
      }
    if (q == 0) {
#pragma unroll
      for (int r = 0; r < 4; r++) {
        int i = i0 + g * 4 + r;
        if (i < E2) {
#pragma unroll
          for (int hh = 0; hh < NH; hh++)
            e_s[(size_t)i * 4 + headbase + hh] = p[hh][r];
        }
      }
    }
  }
}

// ---------------- per-node softmax + aggregation; 4x-unrolled gather, register-only selects ----------------
template <int HC, bool L1MODE>
__global__ __launch_bounds__(256) void aggr_kernel(
    const float* __restrict__ e_s, const unsigned short* __restrict__ xl,
    const int* __restrict__ rowptr, const int* __restrict__ srcpos,
    const float* __restrict__ bias,
    const float* __restrict__ lng, const float* __restrict__ lnb,
    float* __restrict__ xout,
    float* __restrict__ x1out, const float* __restrict__ skipproj,
    float* __restrict__ md, int N) {
  constexpr int CPL = HC / 64;
  int lane = threadIdx.x & 63, wv = threadIdx.x >> 6;
  int stride = gridDim.x * 4;
  const float4* e_s4 = (const float4*)e_s;
  for (int n = blockIdx.x * 4 + wv; n < N; n += stride) {
    int r0 = rowptr[n], r1 = rowptr[n + 1];
    float m0 = -1e30f, m1 = -1e30f, m2 = -1e30f, m3 = -1e30f;
    for (int i = r0 + lane; i < r1; i += 64) {
      float4 v = e_s4[i];
      m0 = fmaxf(m0, v.x);
      m1 = fmaxf(m1, v.y);
      m2 = fmaxf(m2, v.z);
      m3 = fmaxf(m3, v.w);
    }
    m0 = wave_max(m0);
    m1 = wave_max(m1);
    m2 = wave_max(m2);
    m3 = wave_max(m3);
    float d0 = 0.f, d1 = 0.f, d2 = 0.f, d3 = 0.f;
    for (int i = r0 + lane; i < r1; i += 64) {
      float4 v = e_s4[i];
      d0 += __expf(v.x - m0);
      d1 += __expf(v.y - m1);
      d2 += __expf(v.z - m2);
      d3 += __expf(v.w - m3);
    }
    d0 = wave_sum(d0);
    d1 = wave_sum(d1);
    d2 = wave_sum(d2);
    d3 = wave_sum(d3);
    float i0 = 1.f / (d0 + 1e-16f), i1 = 1.f / (d1 + 1e-16f);
    float i2 = 1.f / (d2 + 1e-16f), i3 = 1.f / (d3 + 1e-16f);
    if (lane == 0) {
      float* mp = md + (size_t)n * 8;
      mp[0] = m0; mp[1] = m1; mp[2] = m2; mp[3] = m3;
      mp[4] = i0; mp[5] = i1; mp[6] = i2; mp[7] = i3;
    }
    int h = lane >> 4;
    float mh = (h & 2) ? ((h & 1) ? m3 : m2) : ((h & 1) ? m1 : m0);
    float ih = (h & 2) ? ((h & 1) ? i3 : i2) : ((h & 1) ? i1 : i0);
    float acc[CPL];
#pragma unroll
    for (int j = 0; j < CPL; j++) acc[j] = 0.f;
    int c0 = lane * CPL;
    int i = r0;
    for (; i + 4 <= r1; i += 4) {
      float sh0, sh1, sh2, sh3;
      int sn0, sn1, sn2, sn3;
      {
        float4 a = e_s4[i], b = e_s4[i + 1], c = e_s4[i + 2], d = e_s4[i + 3];
        sh0 = sel4(a, h); sh1 = sel4(b, h); sh2 = sel4(c, h); sh3 = sel4(d, h);
      }
      sn0 = srcpos[i]; sn1 = srcpos[i + 1]; sn2 = srcpos[i + 2]; sn3 = srcpos[i + 3];
      if constexpr (CPL == 2) {
        ushort2 t0 = *(const ushort2*)(xl + (size_t)sn0 * HC + c0);
        ushort2 t1 = *(const ushort2*)(xl + (size_t)sn1 * HC + c0);
        ushort2 t2 = *(const ushort2*)(xl + (size_t)sn2 * HC + c0);
        ushort2 t3 = *(const ushort2*)(xl + (size_t)sn3 * HC + c0);
        float a0 = __expf(sh0 - mh) * ih;
        float a1 = __expf(sh1 - mh) * ih;
        float a2 = __expf(sh2 - mh) * ih;
        float a3 = __expf(sh3 - mh) * ih;
        acc[0] += a0 * bf2f(t0.x) + a1 * bf2f(t1.x) + a2 * bf2f(t2.x) + a3 * bf2f(t3.x);
        acc[1] += a0 * bf2f(t0.y) + a1 * bf2f(t1.y) + a2 * bf2f(t2.y) + a3 * bf2f(t3.y);
      } else {
        ushort4 t0 = *(const ushort4*)(xl + (size_t)sn0 * HC + c0);
        ushort4 t1 = *(const ushort4*)(xl + (size_t)sn1 * HC + c0);
        ushort4 t2 = *(const ushort4*)(xl + (size_t)sn2 * HC + c0);
        ushort4 t3 = *(const ushort4*)(xl + (size_t)sn3 * HC + c0);
        float a0 = __expf(sh0 - mh) * ih;
        float a1 = __expf(sh1 - mh) * ih;
        float a2 = __expf(sh2 - mh) * ih;
        float a3 = __expf(sh3 - mh) * ih;
        acc[0] += a0 * bf2f(t0.x) + a1 * bf2f(t1.x) + a2 * bf2f(t2.x) + a3 * bf2f(t3.x);
        acc[1] += a0 * bf2f(t0.y) + a1 * bf2f(t1.y) + a2 * bf2f(t2.y) + a3 * bf2f(t3.y);
        acc[2] += a0 * bf2f(t0.z) + a1 * bf2f(t1.z) + a2 * bf2f(t2.z) + a3 * bf2f(t3.z);
        acc[3] += a0 * bf2f(t0.w) + a1 * bf2f(t1.w) + a2 * bf2f(t2.w) + a3 * bf2f(t3.w);
      }
    }
    for (; i < r1; i++) {
      float sh = sel4(e_s4[i], h);
      float a = __expf(sh - mh) * ih;
      int sn = srcpos[i];
      const unsigned short* xp = xl + (size_t)sn * HC + c0;
      if constexpr (CPL == 2) {
        ushort2 t = *(const ushort2*)xp;
        acc[0] += a * bf2f(t.x);
        acc[1] += a * bf2f(t.y);
      } else {
        ushort4 t = *(const ushort4*)xp;
        acc[0] += a * bf2f(t.x);
        acc[1] += a * bf2f(t.y);
        acc[2] += a * bf2f(t.z);
        acc[3] += a * bf2f(t.w);
      }
    }
    float vals[CPL];
    float vs = 0.f, vq = 0.f;
#pragma unroll
    for (int j = 0; j < CPL; j++) {
      float t = acc[j] + bias[c0 + j];
      vals[j] = t;
      vs += t;
      vq += t * t;
    }
    vs = wave_sum(vs);
    vq = wave_sum(vq);
    float mean = vs * (1.f / HC);
    float var = vq * (1.f / HC) - mean * mean;
    float rstd = rsqrtf(fmaxf(var, 0.f) + 1e-5f);
#pragma unroll
    for (int j = 0; j < CPL; j++) {
      int c = c0 + j;
      float y = (vals[j] - mean) * rstd * lng[c] + lnb[c];
      y = leakyf(y, 0.01f);
      if constexpr (L1MODE) {
        x1out[(size_t)n * HC + c] = y;
        xout[(size_t)n * HC + c] = 0.01f * skipproj[(size_t)n * HC + c] + y;
      } else {
        xout[(size_t)n * HC + c] = y;
      }
    }
  }
}

// ---------------- alpha: coalesced e_s/dstpos read, md L2-hit, one scattered 16B write ----------------
__global__ __launch_bounds__(256) void alpha_kernel(
    const float* __restrict__ e_s, const int* __restrict__ csr,
    const int* __restrict__ dstpos, const float* __restrict__ md,
    float* __restrict__ alpha_out, int E2) {
  int i = blockIdx.x * 256 + threadIdx.x;
  if (i < E2) {
    float4 sv = ((const float4*)e_s)[i];
    int d = dstpos[i];
    const float* mp = md + (size_t)d * 8;
    float4 a;
    a.x = __expf(sv.x - mp[0]) * mp[4];
    a.y = __expf(sv.y - mp[1]) * mp[5];
    a.z = __expf(sv.z - mp[2]) * mp[6];
    a.w = __expf(sv.w - mp[3]) * mp[7];
    ((float4*)alpha_out)[csr[i]] = a;
  }
}

extern "C" void kernel_launch(void* const* d_in, const int* in_sizes, int n_in,
                              void* d_out, int out_size, void* d_ws, size_t ws_size,
                              hipStream_t stream) {
  (void)n_in;
  (void)out_size;
  (void)ws_size;
  const float* x_in = (const float*)d_in[0];
  const int* edge_index = (const int*)d_in[1];
  const float* edge_attr = (const float*)d_in[2];
  const float* bn0_g = (const float*)d_in[3];
  const float* bn0_b = (const float*)d_in[4];
  const float* bn0_m = (const float*)d_in[5];
  const float* bn0_v = (const float*)d_in[6];
  const float* eeW1 = (const float*)d_in[7];
  const float* eeb1 = (const float*)d_in[8];
  const float* eeW2 = (const float*)d_in[9];
  const float* eeb2 = (const float*)d_in[10];
  const float* g1_Wl = (const float*)d_in[11];
  const float* g1_bl = (const float*)d_in[12];
  const float* g1_Wr = (const float*)d_in[13];
  const float* g1_br = (const float*)d_in[14];
  const float* g1_We = (const float*)d_in[15];
  const float* g1_att = (const float*)d_in[16];
  const float* g1_bias = (const float*)d_in[17];
  const float* g2_Wl = (const float*)d_in[18];
  const float* g2_bl = (const float*)d_in[19];
  const float* g2_Wr = (const float*)d_in[20];
  const float* g2_br = (const float*)d_in[21];
  const float* g2_We = (const float*)d_in[22];
  const float* g2_att = (const float*)d_in[23];
  const float* g2_bias = (const float*)d_in[24];
  const float* g3_Wl = (const float*)d_in[25];
  const float* g3_bl = (const float*)d_in[26];
  const float* g3_Wr = (const float*)d_in[27];
  const float* g3_br = (const float*)d_in[28];
  const float* g3_We = (const float*)d_in[29];
  const float* g3_att = (const float*)d_in[30];
  const float* g3_bias = (const float*)d_in[31];
  const float* ln1_g = (const float*)d_in[32];
  const float* ln1_b = (const float*)d_in[33];
  const float* ln2_g = (const float*)d_in[34];
  const float* ln2_b = (const float*)d_in[35];
  const float* ln3_g = (const float*)d_in[36];
  const float* ln3_b = (const float*)d_in[37];
  const float* skip_W = (const float*)d_in[38];
  const float* skip_b = (const float*)d_in[39];
  const float* alpha_p = (const float*)d_in[40];
  const float* fp_W = (const float*)d_in[41];
  const float* fp_b = (const float*)d_in[42];
  const float* np_W1 = (const float*)d_in[43];
  const float* np_b1 = (const float*)d_in[44];
  const float* np_W2 = (const float*)d_in[45];
  const float* np_b2 = (const float*)d_in[46];
  const float* np_W3 = (const float*)d_in[47];
  const float* np_b3 = (const float*)d_in[48];

  const int N = in_sizes[0] / 64;
  const int E = in_sizes[2] / 16;
  const int E2 = E + N;
  const int* src0 = edge_index;
  const int* dst0 = edge_index + E;

  float* ws = (float*)d_ws;
  size_t off = 0;
  float* x = ws + off;         off += (size_t)N * 64;
  unsigned short* ea_csr = (unsigned short*)(ws + off); off += (size_t)E2 * 32;
  unsigned short* xl = (unsigned short*)(ws + off);    off += (size_t)N * 128;
  unsigned short* xr = (unsigned short*)(ws + off);    off += (size_t)N * 128;
  float* skipproj = ws + off;  off += (size_t)N * 128;  // reused as h1 at the end
  float* x1 = ws + off;        off += (size_t)N * 128;
  float* skip1 = ws + off;     off += (size_t)N * 128;
  float* x2 = ws + off;        off += (size_t)N * 128;
  float* x3 = ws + off;        off += (size_t)N * 256;
  float* e_s = ws + off;       off += (size_t)E2 * 4;
  float* h2 = ws + off;        off += (size_t)N * 64;
  float* md = ws + off;        off += (size_t)N * 8;
  int* counts = (int*)(ws + off);
  int* rowptr = counts + N;
  int* fill = rowptr + N + 1;
  int* csr = fill + N;
  int* srcpos = csr + E2;
  int* dstpos = srcpos + E2;
  int* inv = dstpos + E2;
  off += (size_t)(3 * N + 1 + 4 * E2);
  off = (off + 3) & ~(size_t)3;
  unsigned short* wtp = (unsigned short*)(ws + off);
  auto alloc_wt = [&](int elems) {
    unsigned short* p = wtp;
    wtp += (elems + 7) & ~7;
    return p;
  };
  unsigned short* wt_g1l = alloc_wt(64 * 128);
  unsigned short* wt_g1r = alloc_wt(64 * 128);
  unsigned short* wt_skip = alloc_wt(64 * 128);
  unsigned short* wt_g2l = alloc_wt(128 * 128);
  unsigned short* wt_g2r = alloc_wt(128 * 128);
  unsigned short* wt_g3l = alloc_wt(128 * 256);
  unsigned short* wt_g3r = alloc_wt(128 * 256);
  unsigned short* wt_fp = alloc_wt(128 * 256);
  unsigned short* wt_np1 = alloc_wt(256 * 128);
  unsigned short* wt_np2 = alloc_wt(128 * 64);
  unsigned short* wt_np3 = alloc_wt(64 * 1);
  unsigned short* wt_ee1 = alloc_wt(16 * 128);
  unsigned short* wt_ee2 = alloc_wt(128 * 64);

  float* out = (float*)d_out;
  float* xf = out;
  float* npout = out + (size_t)N * 256;
  float* a1 = npout + N;
  float* a2 = a1 + (size_t)E2 * 4;
  float* a3 = a2 + (size_t)E2 * 4;

  WJobs jobs;
  jobs.j[0] = {g1_Wl, wt_g1l, 64, 128};
  jobs.j[1] = {g1_Wr, wt_g1r, 64, 128};
  jobs.j[2] = {skip_W, wt_skip, 64, 128};
  jobs.j[3] = {g2_Wl, wt_g2l, 128, 128};
  jobs.j[4] = {g2_Wr, wt_g2r, 128, 128};
  jobs.j[5] = {g3_Wl, wt_g3l, 128, 256};
  jobs.j[6] = {g3_Wr, wt_g3r, 128, 256};
  jobs.j[7] = {fp_W, wt_fp, 128, 256};
  jobs.j[8] = {np_W1, wt_np1, 256, 128};
  jobs.j[9] = {np_W2, wt_np2, 128, 64};
  jobs.j[10] = {np_W3, wt_np3, 64, 1};
  jobs.j[11] = {eeW1, wt_ee1, 16, 128};
  jobs.j[12] = {eeW2, wt_ee2, 128, 64};

  hipMemsetAsync(counts, 0, (size_t)N * sizeof(int), stream);
  wt_kernel<<<dim3(64, 13), 256, 0, stream>>>(jobs);
  bn_kernel<<<(N * 64 + 255) / 256, 256, 0, stream>>>(x_in, bn0_g, bn0_b, bn0_m, bn0_v, x, N * 64);
  count_kernel<<<(E2 + 255) / 256, 256, 0, stream>>>(dst0, counts, E, E2);
  scan_kernel<<<1, 1024, 0, stream>>>(counts, rowptr, fill, N);
  fill_kernel<<<(E2 + 255) / 256, 256, 0, stream>>>(src0, dst0, fill, csr, srcpos, dstpos, inv, E, E2);
  edge_enc_kernel<<<1280, 256, 0, stream>>>(edge_attr, wt_ee1, eeb1, wt_ee2, eeb2, ea_csr, inv, E);
  loopattr_kernel<<<(N + 3) / 4, 256, 0, stream>>>(ea_csr, rowptr, csr, N, E);

  auto gemm = [&](int mode, const float* A, const unsigned short* BT, const float* bias,
                  void* Cp, int M, int K, int Nc, const float* aux) {
    dim3 gdim((Nc + 63) / 64, (M + 63) / 64);
    switch (mode) {
      case 0: gemm_mfma_kernel<0><<<gdim, 256, 0, stream>>>(A, BT, bias, Cp, M, K, Nc, nullptr, nullptr); break;
      case 2: gemm_mfma_kernel<2><<<gdim, 256, 0, stream>>>(A, BT, bias, Cp, M, K, Nc, nullptr, nullptr); break;
      case 3: gemm_mfma_kernel<3><<<gdim, 256, 0, stream>>>(A, BT, bias, Cp, M, K, Nc, aux, alpha_p); break;
    }
  };
  auto gemm_batch = [&](const float* A, int M, int K, int Nc, GJobs gj, int nz) {
    dim3 gdim((Nc + 63) / 64, (M + 63) / 64, nz);
    gemm_mfma_batched<<<gdim, 256, 0, stream>>>(A, gj, M, K, Nc);
  };

  const int nblk_node = (N + 3) / 4;
  const int score_blocks = 1024;
  const int nblk_edge = (E2 + 255) / 256;

  // ---- Layer 1 (din=64, HC=128, C=32) ----
  {
    GJobs gj;
    gj.j[0] = {wt_g1l, g1_bl, xl, 1};
    gj.j[1] = {wt_g1r, g1_br, xr, 1};
    gj.j[2] = {wt_skip, skip_b, skipproj, 0};
    gemm_batch(x, N, 64, 128, gj, 3);
  }
  score_mfma_kernel<32, false><<<score_blocks, 256, 0, stream>>>(ea_csr, xl, xr, g1_We, g1_att, srcpos, dstpos, e_s, E2, 128, 0);
  aggr_kernel<128, true><<<nblk_node, 256, 0, stream>>>(e_s, xl, rowptr, srcpos, g1_bias, ln1_g, ln1_b,
                                                        skip1, x1, skipproj, md, N);
  alpha_kernel<<<nblk_edge, 256, 0, stream>>>(e_s, csr, dstpos, md, a1, E2);
  // ---- Layer 2 (din=128, HC=128, C=32) ----
  {
    GJobs gj;
    gj.j[0] = {wt_g2l, g2_bl, xl, 1};
    gj.j[1] = {wt_g2r, g2_br, xr, 1};
    gj.j[2] = {nullptr, nullptr, nullptr, 0};
    gemm_batch(skip1, N, 128, 128, gj, 2);
  }
  score_mfma_kernel<32, false><<<score_blocks, 256, 0, stream>>>(ea_csr, xl, xr, g2_We, g2_att, srcpos, dstpos, e_s, E2, 128, 0);
  aggr_kernel<128, false><<<nblk_node, 256, 0, stream>>>(e_s, xl, rowptr, srcpos, g2_bias, ln2_g, ln2_b,
                                                         x2, nullptr, nullptr, md, N);
  alpha_kernel<<<nblk_edge, 256, 0, stream>>>(e_s, csr, dstpos, md, a2, E2);
  // ---- Layer 3 (din=128, HC=256, C=64): one launch, wave-split col halves ----
  {
    GJobs gj;
    gj.j[0] = {wt_g3l, g3_bl, xl, 1};
    gj.j[1] = {wt_g3r, g3_br, xr, 1};
    gj.j[2] = {nullptr, nullptr, nullptr, 0};
    gemm_batch(x2, N, 128, 256, gj, 2);
  }
  score_mfma_kernel<64, true><<<score_blocks, 256, 0, stream>>>(ea_csr, xl, xr, g3_We, g3_att, srcpos, dstpos, e_s, E2, 256, 0);
  aggr_kernel<256, false><<<nblk_node, 256, 0, stream>>>(e_s, xl, rowptr, srcpos, g3_bias, ln3_g, ln3_b,
                                                         x3, nullptr, nullptr, md, N);
  alpha_kernel<<<nblk_edge, 256, 0, stream>>>(e_s, csr, dstpos, md, a3, E2);
  // ---- Final: xf = s*(x1@fp_W+fp_b) + (1-s)*x3 ; node MLP ----
  gemm(3, x1, wt_fp, fp_b, xf, N, 128, 256, x3);
  gemm(2, xf, wt_np1, np_b1, skipproj, N, 256, 128, nullptr);   // h1
  gemm(2, skipproj, wt_np2, np_b2, h2, N, 128, 64, nullptr);    // h2
  gemm(0, h2, wt_np3, np_b3, npout, N, 64, 1, nullptr);
}